// Round 13
// baseline (331.860 us; speedup 1.0000x reference)
//
#include <hip/hip_runtime.h>
#include <hip/hip_fp16.h>

#define NNODES 50000
#define NEDGES 800000
#define HIDDIM 256
#define EN (NEDGES + NNODES)          // CSR entries incl. self-loops
#define NTILES ((NNODES + 63)/64)     // 782 row-tiles of 64
#define NT64 (NTILES*64)              // padded row count 50048
#define NPART 8                       // dst-partitions (XCD count)

constexpr float NEG = 0.2f;

typedef __attribute__((ext_vector_type(8))) short short8_t;   // bf16x8 MFMA frag
typedef __attribute__((ext_vector_type(4))) float floatx4;    // f32x4 acc

__device__ __forceinline__ float lrelu(float v){ return v >= 0.f ? v : NEG*v; }

__device__ __forceinline__ unsigned short bf16_rn(float x){
  unsigned u = __float_as_uint(x);
  return (unsigned short)((u + 0x7FFFu + ((u >> 16) & 1u)) >> 16);
}

__device__ __forceinline__ float4 ldh4(const __half* p){
  union { float2 f; __half2 h[2]; } u;
  u.f = *reinterpret_cast<const float2*>(p);
  const float2 lo = __half22float2(u.h[0]);
  const float2 hi = __half22float2(u.h[1]);
  return make_float4(lo.x, lo.y, hi.x, hi.y);
}

// ---------------- CSR build (by dst; self-loop implicit +1) ----------------
// dst-partitioned count: atomics stay XCD-local (R9 scatter lesson)
__global__ __launch_bounds__(256) void k_count(const int* __restrict__ ei,
                                               int* counts, int E, int n){
  const int part = blockIdx.x & (NPART-1);
  const int nchunk = gridDim.x >> 3;
  const int chunk = blockIdx.x >> 3;
  const int per = n / NPART;
  const int dlo = part*per, dhi = dlo + per;
  for (int e = chunk*256 + threadIdx.x; e < E; e += nchunk*256){
    const int d = ei[E + e];
    if (d >= dlo && d < dhi) atomicAdd(&counts[d], 1);
  }
}

#define SCAN_CHUNK 2048
__global__ __launch_bounds__(256) void k_scan_a(const int* __restrict__ counts,
                                                int* __restrict__ bsum, int n){
  __shared__ int ws[4];
  const int t = threadIdx.x;
  const int idx0 = blockIdx.x*SCAN_CHUNK + t*8;
  int s = 0;
  #pragma unroll
  for (int i = 0; i < 8; ++i) if (idx0 + i < n) s += counts[idx0 + i] + 1;
  for (int off = 32; off; off >>= 1) s += __shfl_xor(s, off);
  if ((t & 63) == 0) ws[t >> 6] = s;
  __syncthreads();
  if (t == 0) bsum[blockIdx.x] = ws[0] + ws[1] + ws[2] + ws[3];
}
__global__ void k_scan_b(const int* __restrict__ bsum, int* __restrict__ boff,
                         int* __restrict__ offs, int nb, int n){
  if (threadIdx.x == 0){
    int run = 0;
    for (int i = 0; i < nb; ++i){ boff[i] = run; run += bsum[i]; }
    offs[n] = run;
  }
}
__global__ __launch_bounds__(256) void k_scan_c(const int* __restrict__ counts,
                                                const int* __restrict__ boff,
                                                int* __restrict__ offs,
                                                int* __restrict__ cursor, int n){
  __shared__ int sc[256];
  const int t = threadIdx.x;
  const int idx0 = blockIdx.x*SCAN_CHUNK + t*8;
  int v[8], pre[8], s = 0;
  #pragma unroll
  for (int i = 0; i < 8; ++i){
    v[i] = (idx0 + i < n) ? counts[idx0 + i] + 1 : 0;
    pre[i] = s; s += v[i];
  }
  sc[t] = s;
  __syncthreads();
  int run = s;
  for (int off = 1; off < 256; off <<= 1){
    int add = (t >= off) ? sc[t - off] : 0;
    __syncthreads();
    sc[t] += add;
    __syncthreads();
  }
  const int excl = sc[t] - run;
  const int toff = boff[blockIdx.x] + excl;
  #pragma unroll
  for (int i = 0; i < 8; ++i){
    if (idx0 + i < n){
      const int o = toff + pre[i];
      offs[idx0 + i] = o;
      cursor[idx0 + i] = o;
    }
  }
}

// dst-partitioned scatter (R9: kills write-allocate amplification)
__global__ __launch_bounds__(256) void k_scatter(const int* __restrict__ ei, int* cursor,
                          int* __restrict__ esrc, int E, int n){
  const int part = blockIdx.x & (NPART-1);
  const int nchunk = gridDim.x >> 3;
  const int chunk = blockIdx.x >> 3;
  const int per = n / NPART;
  const int dlo = part*per, dhi = dlo + per;
  const int total = E + n;
  for (int e = chunk*256 + threadIdx.x; e < total; e += nchunk*256){
    const int d = (e < E) ? ei[E + e] : (e - E);
    if (d >= dlo && d < dhi){
      const int s = (e < E) ? ei[e] : d;
      esrc[atomicAdd(&cursor[d], 1)] = s;
    }
  }
}

// ---------------- k_wprep: merged weight split + folded attention vectors ---
__global__ __launch_bounds__(256) void k_wprep(
    const float* __restrict__ W1, const float* __restrict__ aS1, const float* __restrict__ aD1,
    const float* __restrict__ W2, const float* __restrict__ aS2, const float* __restrict__ aD2,
    unsigned short* __restrict__ W1hi, unsigned short* __restrict__ W1lo,
    unsigned short* __restrict__ W2hi, unsigned short* __restrict__ W2lo,
    float* __restrict__ va1, float* __restrict__ va2)
{
  const int b = blockIdx.x, t = threadIdx.x;
  if (b < 384){
    const float* W = (b < 128) ? W1 : W2;
    unsigned short* hi = (b < 128) ? W1hi : W2hi;
    unsigned short* lo = (b < 128) ? W1lo : W2lo;
    const int idx = ((b < 128) ? b : (b - 128))*256 + t;
    const int k = idx / HIDDIM, n = idx % HIDDIM;
    const float w = W[idx];
    const unsigned short h = bf16_rn(w);
    const unsigned short l = bf16_rn(w - __uint_as_float((unsigned)h << 16));
    const int p = ((k >> 3)*HIDDIM + n)*8 + (k & 7);
    hi[p] = h; lo[p] = l;
  } else {
    if (t < 128){
      #pragma unroll
      for (int h = 0; h < 4; ++h){
        float s = 0.f, d = 0.f;
        for (int k = 0; k < 64; ++k){
          const float w = W1[t*HIDDIM + h*64 + k];
          s = fmaf(w, aS1[h*64 + k], s);
          d = fmaf(w, aD1[h*64 + k], d);
        }
        va1[t*8 + h] = s;
        va1[t*8 + 4 + h] = d;
      }
    } else {
      for (int c = t - 128; c < 256; c += 128){
        float s = 0.f, d = 0.f;
        for (int j = 0; j < 256; ++j){
          const float w = W2[c*HIDDIM + j];
          s = fmaf(w, aS2[j], s);
          d = fmaf(w, aD2[j], d);
        }
        va2[c*2] = s; va2[c*2+1] = d;
      }
    }
  }
}

// ---------------- k_xh_logits: x -> fp16 copy + layer-1 logits --------------
__global__ __launch_bounds__(256) void k_xh_logits(
    const float* __restrict__ X, const float* __restrict__ va1,
    __half* __restrict__ xh, float* __restrict__ as1, float* __restrict__ ad1, int n)
{
  const int lane = threadIdx.x & 63;
  const int node = blockIdx.x*4 + (threadIdx.x >> 6);
  if (node >= n) return;
  const float2 xv = *reinterpret_cast<const float2*>(X + (size_t)node*128 + 2*lane);
  *reinterpret_cast<__half2*>(xh + (size_t)node*128 + 2*lane) = __float22half2_rn(xv);

  const float4 vs0 = *reinterpret_cast<const float4*>(va1 + (2*lane)*8);
  const float4 vd0 = *reinterpret_cast<const float4*>(va1 + (2*lane)*8 + 4);
  const float4 vs1 = *reinterpret_cast<const float4*>(va1 + (2*lane+1)*8);
  const float4 vd1 = *reinterpret_cast<const float4*>(va1 + (2*lane+1)*8 + 4);
  float ps[4], pd[4];
  ps[0] = xv.x*vs0.x + xv.y*vs1.x;  pd[0] = xv.x*vd0.x + xv.y*vd1.x;
  ps[1] = xv.x*vs0.y + xv.y*vs1.y;  pd[1] = xv.x*vd0.y + xv.y*vd1.y;
  ps[2] = xv.x*vs0.z + xv.y*vs1.z;  pd[2] = xv.x*vd0.z + xv.y*vd1.z;
  ps[3] = xv.x*vs0.w + xv.y*vs1.w;  pd[3] = xv.x*vd0.w + xv.y*vd1.w;
  #pragma unroll
  for (int h = 0; h < 4; ++h)
    for (int off = 32; off; off >>= 1){
      ps[h] += __shfl_xor(ps[h], off);
      pd[h] += __shfl_xor(pd[h], off);
    }
  if (lane == 0){
    *reinterpret_cast<float4*>(as1 + (size_t)node*4) = make_float4(ps[0],ps[1],ps[2],ps[3]);
    *reinterpret_cast<float4*>(ad1 + (size_t)node*4) = make_float4(pd[0],pd[1],pd[2],pd[3]);
  }
}

// ---------------- k_agg1: FUSED softmax + gather (layer 1) ------------------
// half-wave per node; lane l2 owns channels [4*l2,4*l2+4); weights computed
// inline from L2-resident as1/ad1 (800 KB each); dsum per-lane (all lanes see
// all edges -> identical, no reduction). Output bf16 [node][head][128].
__global__ __launch_bounds__(256) void k_agg1(
    const __half* __restrict__ xh,
    const float* __restrict__ as1, const float* __restrict__ ad1,
    const int* __restrict__ offs, const int* __restrict__ esrc,
    unsigned short* __restrict__ xagg, int n)
{
  constexpr float SHIFT = 2.0f;
  const int l2 = threadIdx.x & 31;
  const int node = blockIdx.x*8 + (threadIdx.x >> 5);
  if (node >= n) return;
  const int start = offs[node], end = offs[node+1];
  const float4 adv4 = *reinterpret_cast<const float4*>(ad1 + (size_t)node*4);
  const float adv[4] = {adv4.x - SHIFT, adv4.y - SHIFT, adv4.z - SHIFT, adv4.w - SHIFT};
  const __half* hp = xh + 4*l2;

  float acc[4][4] = {};   // [head][ch]
  float dsum[4] = {0.f, 0.f, 0.f, 0.f};
  int e = start;
  for (; e + 8 <= end; e += 8){
    int s[8]; float2 xv[8];
    #pragma unroll
    for (int i = 0; i < 8; ++i) s[i] = esrc[e+i];
    #pragma unroll
    for (int i = 0; i < 8; ++i) xv[i] = *reinterpret_cast<const float2*>(hp + (size_t)s[i]*128);
    #pragma unroll
    for (int i = 0; i < 8; ++i){
      const float4 av = *reinterpret_cast<const float4*>(as1 + (size_t)s[i]*4);
      const float a[4] = {av.x, av.y, av.z, av.w};
      float ph[4];
      #pragma unroll
      for (int h = 0; h < 4; ++h){
        ph[h] = __expf(lrelu(a[h] + adv[h] + SHIFT) - SHIFT);
        dsum[h] += ph[h];
      }
      union { float2 f; __half2 h2[2]; } ux; ux.f = xv[i];
      const float2 x01 = __half22float2(ux.h2[0]);
      const float2 x23 = __half22float2(ux.h2[1]);
      const float xc[4] = {x01.x, x01.y, x23.x, x23.y};
      #pragma unroll
      for (int h = 0; h < 4; ++h)
        #pragma unroll
        for (int c = 0; c < 4; ++c)
          acc[h][c] = fmaf(ph[h], xc[c], acc[h][c]);
    }
  }
  for (; e < end; ++e){
    const int s = esrc[e];
    const float4 av = *reinterpret_cast<const float4*>(as1 + (size_t)s*4);
    const float a[4] = {av.x, av.y, av.z, av.w};
    float ph[4];
    #pragma unroll
    for (int h = 0; h < 4; ++h){
      ph[h] = __expf(lrelu(a[h] + adv[h] + SHIFT) - SHIFT);
      dsum[h] += ph[h];
    }
    union { float2 f; __half2 h2[2]; } ux;
    ux.f = *reinterpret_cast<const float2*>(hp + (size_t)s*128);
    const float2 x01 = __half22float2(ux.h2[0]);
    const float2 x23 = __half22float2(ux.h2[1]);
    const float xc[4] = {x01.x, x01.y, x23.x, x23.y};
    #pragma unroll
    for (int h = 0; h < 4; ++h)
      #pragma unroll
      for (int c = 0; c < 4; ++c)
        acc[h][c] = fmaf(ph[h], xc[c], acc[h][c]);
  }
  #pragma unroll
  for (int h = 0; h < 4; ++h){
    const float rd = 1.f/(dsum[h] + 1e-16f);
    uint2 pk;
    pk.x = (unsigned)bf16_rn(acc[h][0]*rd) | ((unsigned)bf16_rn(acc[h][1]*rd) << 16);
    pk.y = (unsigned)bf16_rn(acc[h][2]*rd) | ((unsigned)bf16_rn(acc[h][3]*rd) << 16);
    *reinterpret_cast<uint2*>(xagg + (size_t)node*512 + h*128 + 4*l2) = pk;
  }
}

// ---------------- k_gemm1: h1e = ELU(xagg @ blockdiag(W1) + b1) -------------
__global__ __launch_bounds__(256) void k_gemm1(
    const unsigned short* __restrict__ Xagg,
    const unsigned short* __restrict__ Bhi, const unsigned short* __restrict__ Blo,
    const float* __restrict__ b1, const float* __restrict__ va2,
    __half* __restrict__ h1e, float* __restrict__ as2, float* __restrict__ ad2, int M)
{
  __shared__ float lred_s[64][4], lred_d[64][4];
  const int tid = threadIdx.x;
  const int w = tid >> 6, l = tid & 63;
  const int lr = l & 15, lg = l >> 4;
  const int row0 = blockIdx.x*64;
  const int n0 = w*64;
  floatx4 acc[4][4] = {};

  for (int ks = 0; ks < 4; ++ks){
    short8_t a_[4], bh[4], bl[4];
    #pragma unroll
    for (int m = 0; m < 4; ++m){
      const size_t ao = (size_t)(row0 + 16*m + lr)*512 + w*128 + ks*32 + lg*8;
      a_[m] = *reinterpret_cast<const short8_t*>(&Xagg[ao]);
    }
    #pragma unroll
    for (int n = 0; n < 4; ++n){
      const int boff = (((ks*4 + lg)*HIDDIM) + n0 + 16*n + lr)*8;
      bh[n] = *reinterpret_cast<const short8_t*>(&Bhi[boff]);
      bl[n] = *reinterpret_cast<const short8_t*>(&Blo[boff]);
    }
    #pragma unroll
    for (int m = 0; m < 4; ++m)
      #pragma unroll
      for (int n = 0; n < 4; ++n){
        acc[m][n] = __builtin_amdgcn_mfma_f32_16x16x32_bf16(a_[m], bh[n], acc[m][n], 0,0,0);
        acc[m][n] = __builtin_amdgcn_mfma_f32_16x16x32_bf16(a_[m], bl[n], acc[m][n], 0,0,0);
      }
  }

  float bcol[4], v2s[4], v2d[4];
  #pragma unroll
  for (int n = 0; n < 4; ++n){
    const int col = n0 + 16*n + lr;
    bcol[n] = b1[col];
    v2s[n] = va2[col*2];
    v2d[n] = va2[col*2+1];
  }
  #pragma unroll
  for (int m = 0; m < 4; ++m){
    #pragma unroll
    for (int r = 0; r < 4; ++r){
      const int row = row0 + 16*m + lg*4 + r;
      float ps = 0.f, pd = 0.f;
      #pragma unroll
      for (int n = 0; n < 4; ++n){
        float v = acc[m][n][r] + bcol[n];
        v = v > 0.f ? v : __expf(v) - 1.f;           // ELU
        if (row < M) h1e[(size_t)row*HIDDIM + n0 + 16*n + lr] = __float2half(v);
        ps = fmaf(v, v2s[n], ps);
        pd = fmaf(v, v2d[n], pd);
      }
      #pragma unroll
      for (int off = 1; off <= 8; off <<= 1){
        ps += __shfl_xor(ps, off);
        pd += __shfl_xor(pd, off);
      }
      const int rloc = 16*m + lg*4 + r;
      if (lr == 0){ lred_s[rloc][w] = ps; lred_d[rloc][w] = pd; }
    }
  }
  __syncthreads();
  if (tid < 64 && row0 + tid < M){
    as2[row0+tid] = lred_s[tid][0]+lred_s[tid][1]+lred_s[tid][2]+lred_s[tid][3];
    ad2[row0+tid] = lred_d[tid][0]+lred_d[tid][1]+lred_d[tid][2]+lred_d[tid][3];
  }
}

// ---------------- k_agg2: fused softmax + gather (layer 2) ------------------
__global__ __launch_bounds__(256) void k_agg2(
    const __half* __restrict__ Hs,
    const float* __restrict__ as2, const float* __restrict__ ad2,
    const int* __restrict__ offs, const int* __restrict__ esrc,
    unsigned short* __restrict__ xagg2, int n)
{
  constexpr float SHIFT = 4.0f;
  const int lane = threadIdx.x & 63;
  const int node = blockIdx.x*4 + (threadIdx.x >> 6);
  if (node >= n) return;
  const int start = offs[node], end = offs[node+1];
  const float adn = ad2[node];
  const __half* hp = Hs + 4*lane;

  float4 a0 = {0,0,0,0}, a1 = {0,0,0,0}, a2 = {0,0,0,0}, a3 = {0,0,0,0};
  float dsum = 0.f;
  int e = start;
  for (; e + 4 <= end; e += 4){
    const int s0 = esrc[e+0], s1 = esrc[e+1], s2 = esrc[e+2], s3 = esrc[e+3];
    const float w0 = __expf(lrelu(as2[s0] + adn) - SHIFT);
    const float w1 = __expf(lrelu(as2[s1] + adn) - SHIFT);
    const float w2 = __expf(lrelu(as2[s2] + adn) - SHIFT);
    const float w3 = __expf(lrelu(as2[s3] + adn) - SHIFT);
    dsum += (w0 + w1) + (w2 + w3);
    const float4 h0 = ldh4(hp + (size_t)s0*HIDDIM);
    const float4 h1 = ldh4(hp + (size_t)s1*HIDDIM);
    const float4 h2 = ldh4(hp + (size_t)s2*HIDDIM);
    const float4 h3 = ldh4(hp + (size_t)s3*HIDDIM);
    a0.x = fmaf(w0, h0.x, a0.x); a0.y = fmaf(w0, h0.y, a0.y);
    a0.z = fmaf(w0, h0.z, a0.z); a0.w = fmaf(w0, h0.w, a0.w);
    a1.x = fmaf(w1, h1.x, a1.x); a1.y = fmaf(w1, h1.y, a1.y);
    a1.z = fmaf(w1, h1.z, a1.z); a1.w = fmaf(w1, h1.w, a1.w);
    a2.x = fmaf(w2, h2.x, a2.x); a2.y = fmaf(w2, h2.y, a2.y);
    a2.z = fmaf(w2, h2.z, a2.z); a2.w = fmaf(w2, h2.w, a2.w);
    a3.x = fmaf(w3, h3.x, a3.x); a3.y = fmaf(w3, h3.y, a3.y);
    a3.z = fmaf(w3, h3.z, a3.z); a3.w = fmaf(w3, h3.w, a3.w);
  }
  for (; e < end; ++e){
    const int s = esrc[e];
    const float w = __expf(lrelu(as2[s] + adn) - SHIFT);
    dsum += w;
    const float4 hv = ldh4(hp + (size_t)s*HIDDIM);
    a0.x = fmaf(w, hv.x, a0.x); a0.y = fmaf(w, hv.y, a0.y);
    a0.z = fmaf(w, hv.z, a0.z); a0.w = fmaf(w, hv.w, a0.w);
  }
  const float rd = 1.f/(dsum + 1e-16f);
  float4 acc;
  acc.x = ((a0.x + a1.x) + (a2.x + a3.x)) * rd;
  acc.y = ((a0.y + a1.y) + (a2.y + a3.y)) * rd;
  acc.z = ((a0.z + a1.z) + (a2.z + a3.z)) * rd;
  acc.w = ((a0.w + a1.w) + (a2.w + a3.w)) * rd;

  uint2 pk;
  pk.x = (unsigned)bf16_rn(acc.x) | ((unsigned)bf16_rn(acc.y) << 16);
  pk.y = (unsigned)bf16_rn(acc.z) | ((unsigned)bf16_rn(acc.w) << 16);
  *reinterpret_cast<uint2*>(xagg2 + (size_t)node*HIDDIM + 4*lane) = pk;
}

// ---------------- k_gemm2: out = xagg2 @ W2 + b2 ----------------------------
__global__ __launch_bounds__(256) void k_gemm2(
    const unsigned short* __restrict__ Xagg2,
    const unsigned short* __restrict__ Bhi, const unsigned short* __restrict__ Blo,
    const float* __restrict__ b2, float* __restrict__ Out, int M)
{
  const int tid = threadIdx.x;
  const int w = tid >> 6, l = tid & 63;
  const int lr = l & 15, lg = l >> 4;
  const int row0 = blockIdx.x*64;
  const int n0 = w*64;
  floatx4 acc[4][4] = {};

  for (int ks = 0; ks < 8; ++ks){
    short8_t a_[4], bh[4], bl[4];
    #pragma unroll
    for (int m = 0; m < 4; ++m){
      const size_t ao = (size_t)(row0 + 16*m + lr)*HIDDIM + ks*32 + lg*8;
      a_[m] = *reinterpret_cast<const short8_t*>(&Xagg2[ao]);
    }
    #pragma unroll
    for (int n = 0; n < 4; ++n){
      const int boff = (((ks*4 + lg)*HIDDIM) + n0 + 16*n + lr)*8;
      bh[n] = *reinterpret_cast<const short8_t*>(&Bhi[boff]);
      bl[n] = *reinterpret_cast<const short8_t*>(&Blo[boff]);
    }
    #pragma unroll
    for (int m = 0; m < 4; ++m)
      #pragma unroll
      for (int n = 0; n < 4; ++n){
        acc[m][n] = __builtin_amdgcn_mfma_f32_16x16x32_bf16(a_[m], bh[n], acc[m][n], 0,0,0);
        acc[m][n] = __builtin_amdgcn_mfma_f32_16x16x32_bf16(a_[m], bl[n], acc[m][n], 0,0,0);
      }
  }

  float bcol[4];
  #pragma unroll
  for (int n = 0; n < 4; ++n) bcol[n] = b2[n0 + 16*n + lr];
  #pragma unroll
  for (int m = 0; m < 4; ++m){
    #pragma unroll
    for (int r = 0; r < 4; ++r){
      const int row = row0 + 16*m + lg*4 + r;
      if (row < M){
        #pragma unroll
        for (int n = 0; n < 4; ++n)
          Out[(size_t)row*HIDDIM + n0 + 16*n + lr] = acc[m][n][r] + bcol[n];
      }
    }
  }
}

// ---------------- launch ----------------
extern "C" void kernel_launch(void* const* d_in, const int* in_sizes, int n_in,
                              void* d_out, int out_size, void* d_ws, size_t ws_size,
                              hipStream_t stream)
{
  const float* x    = (const float*)d_in[0];
  const int*   ei   = (const int*)  d_in[1];
  const float* W1   = (const float*)d_in[2];
  const float* aS1  = (const float*)d_in[3];
  const float* aD1  = (const float*)d_in[4];
  const float* b1   = (const float*)d_in[5];
  const float* W2   = (const float*)d_in[6];
  const float* aS2  = (const float*)d_in[7];
  const float* aD2  = (const float*)d_in[8];
  const float* b2   = (const float*)d_in[9];
  float* out = (float*)d_out;

  char* ws = (char*)d_ws;
  size_t off = 0;
  auto alloc = [&](size_t bytes){ void* p = ws + off; off += (bytes + 255) & ~255ull; return p; };

  unsigned short* xagg  = (unsigned short*)alloc((size_t)NT64*512*sizeof(short)); // 51.2 MB
  __half*         h1e   = (__half*)alloc((size_t)NT64*HIDDIM*sizeof(__half));     // 25.6 MB
  unsigned short* xagg2 = (unsigned short*)alloc((size_t)NT64*HIDDIM*sizeof(short)); // 25.6 MB
  __half*         xh    = (__half*)xagg2;   // alias: xh dead before xagg2 written
  float* as1    = (float*)alloc((size_t)NNODES*4*sizeof(float));
  float* ad1    = (float*)alloc((size_t)NNODES*4*sizeof(float));
  float* as2    = (float*)alloc((size_t)NNODES*sizeof(float));
  float* ad2    = (float*)alloc((size_t)NNODES*sizeof(float));
  float* va1    = (float*)alloc(128*8*sizeof(float));
  float* va2    = (float*)alloc(256*2*sizeof(float));
  unsigned short* W1hi = (unsigned short*)alloc((size_t)128*HIDDIM*sizeof(short));
  unsigned short* W1lo = (unsigned short*)alloc((size_t)128*HIDDIM*sizeof(short));
  unsigned short* W2hi = (unsigned short*)alloc((size_t)256*HIDDIM*sizeof(short));
  unsigned short* W2lo = (unsigned short*)alloc((size_t)256*HIDDIM*sizeof(short));
  int*   counts = (int*)alloc((size_t)NNODES*sizeof(int));
  int*   offs   = (int*)alloc((size_t)(NNODES+1)*sizeof(int));
  int*   cursor = (int*)alloc((size_t)NNODES*sizeof(int));
  int*   bsum   = (int*)alloc(64*sizeof(int));
  int*   boff   = (int*)alloc(64*sizeof(int));
  int*   esrc   = (int*)alloc((size_t)EN*sizeof(int));

  const int nscan = (NNODES + SCAN_CHUNK - 1)/SCAN_CHUNK;   // 25
  const int node_grid = (NNODES + 3)/4;                     // 12500

  // CSR by dst (partitioned count + scatter; implicit self-loop via +1 in scans)
  hipMemsetAsync(counts, 0, (size_t)NNODES*sizeof(int), stream);
  k_count     <<<NPART*120, 256, 0, stream>>>(ei, counts, NEDGES, NNODES);
  k_scan_a    <<<nscan, 256, 0, stream>>>(counts, bsum, NNODES);
  k_scan_b    <<<1, 64, 0, stream>>>(bsum, boff, offs, nscan, NNODES);
  k_scan_c    <<<nscan, 256, 0, stream>>>(counts, boff, offs, cursor, NNODES);
  k_scatter   <<<NPART*120, 256, 0, stream>>>(ei, cursor, esrc, NEDGES, NNODES);

  // weight prep (merged) + x fp16 copy / layer-1 logits
  k_wprep<<<385, 256, 0, stream>>>(W1, aS1, aD1, W2, aS2, aD2,
                                   W1hi, W1lo, W2hi, W2lo, va1, va2);
  k_xh_logits<<<node_grid, 256, 0, stream>>>(x, va1, xh, as1, ad1, NNODES);

  // layer 1: FUSED softmax+aggregate raw x -> transform (+ layer-2 logits)
  k_agg1<<<(NNODES+7)/8, 256, 0, stream>>>(xh, as1, ad1, offs, esrc, xagg, NNODES);
  k_gemm1<<<NTILES, 256, 0, stream>>>(xagg, W1hi, W1lo, b1, va2, h1e, as2, ad2, NNODES);

  // layer 2: FUSED softmax+aggregate -> transform
  k_agg2<<<node_grid, 256, 0, stream>>>(h1e, as2, ad2, offs, esrc, xagg2, NNODES);
  k_gemm2<<<NTILES, 256, 0, stream>>>(xagg2, W2hi, W2lo, b2, out, NNODES);
}

// Round 14
// 322.598 us; speedup vs baseline: 1.0287x; 1.0287x over previous
//
#include <hip/hip_runtime.h>
#include <hip/hip_fp16.h>

#define NNODES 50000
#define NEDGES 800000
#define HIDDIM 256
#define EN (NEDGES + NNODES)          // CSR entries incl. self-loops
#define NTILES ((NNODES + 63)/64)     // 782 row-tiles of 64
#define NT64 (NTILES*64)              // padded row count 50048
#define NPART 8                       // dst-partitions (XCD count)

constexpr float NEG = 0.2f;

typedef __attribute__((ext_vector_type(8))) short short8_t;   // bf16x8 MFMA frag
typedef __attribute__((ext_vector_type(4))) float floatx4;    // f32x4 acc

__device__ __forceinline__ float lrelu(float v){ return v >= 0.f ? v : NEG*v; }

__device__ __forceinline__ unsigned short bf16_rn(float x){
  unsigned u = __float_as_uint(x);
  return (unsigned short)((u + 0x7FFFu + ((u >> 16) & 1u)) >> 16);
}

__device__ __forceinline__ float4 ldh4(const __half* p){
  union { float2 f; __half2 h[2]; } u;
  u.f = *reinterpret_cast<const float2*>(p);
  const float2 lo = __half22float2(u.h[0]);
  const float2 hi = __half22float2(u.h[1]);
  return make_float4(lo.x, lo.y, hi.x, hi.y);
}

// ---------------- CSR build (by dst; self-loop implicit +1) ----------------
// dst-partitioned count: atomics stay XCD-local (R9 scatter lesson)
__global__ __launch_bounds__(256) void k_count(const int* __restrict__ ei,
                                               int* counts, int E, int n){
  const int part = blockIdx.x & (NPART-1);
  const int nchunk = gridDim.x >> 3;
  const int chunk = blockIdx.x >> 3;
  const int per = n / NPART;
  const int dlo = part*per, dhi = dlo + per;
  for (int e = chunk*256 + threadIdx.x; e < E; e += nchunk*256){
    const int d = ei[E + e];
    if (d >= dlo && d < dhi) atomicAdd(&counts[d], 1);
  }
}

#define SCAN_CHUNK 2048
__global__ __launch_bounds__(256) void k_scan_a(const int* __restrict__ counts,
                                                int* __restrict__ bsum, int n){
  __shared__ int ws[4];
  const int t = threadIdx.x;
  const int idx0 = blockIdx.x*SCAN_CHUNK + t*8;
  int s = 0;
  #pragma unroll
  for (int i = 0; i < 8; ++i) if (idx0 + i < n) s += counts[idx0 + i] + 1;
  for (int off = 32; off; off >>= 1) s += __shfl_xor(s, off);
  if ((t & 63) == 0) ws[t >> 6] = s;
  __syncthreads();
  if (t == 0) bsum[blockIdx.x] = ws[0] + ws[1] + ws[2] + ws[3];
}
__global__ void k_scan_b(const int* __restrict__ bsum, int* __restrict__ boff,
                         int* __restrict__ offs, int nb, int n){
  if (threadIdx.x == 0){
    int run = 0;
    for (int i = 0; i < nb; ++i){ boff[i] = run; run += bsum[i]; }
    offs[n] = run;
  }
}
__global__ __launch_bounds__(256) void k_scan_c(const int* __restrict__ counts,
                                                const int* __restrict__ boff,
                                                int* __restrict__ offs,
                                                int* __restrict__ cursor, int n){
  __shared__ int sc[256];
  const int t = threadIdx.x;
  const int idx0 = blockIdx.x*SCAN_CHUNK + t*8;
  int v[8], pre[8], s = 0;
  #pragma unroll
  for (int i = 0; i < 8; ++i){
    v[i] = (idx0 + i < n) ? counts[idx0 + i] + 1 : 0;
    pre[i] = s; s += v[i];
  }
  sc[t] = s;
  __syncthreads();
  int run = s;
  for (int off = 1; off < 256; off <<= 1){
    int add = (t >= off) ? sc[t - off] : 0;
    __syncthreads();
    sc[t] += add;
    __syncthreads();
  }
  const int excl = sc[t] - run;
  const int toff = boff[blockIdx.x] + excl;
  #pragma unroll
  for (int i = 0; i < 8; ++i){
    if (idx0 + i < n){
      const int o = toff + pre[i];
      offs[idx0 + i] = o;
      cursor[idx0 + i] = o;
    }
  }
}

// dst-partitioned scatter (R9: kills write-allocate amplification)
__global__ __launch_bounds__(256) void k_scatter(const int* __restrict__ ei, int* cursor,
                          int* __restrict__ esrc, int E, int n){
  const int part = blockIdx.x & (NPART-1);
  const int nchunk = gridDim.x >> 3;
  const int chunk = blockIdx.x >> 3;
  const int per = n / NPART;
  const int dlo = part*per, dhi = dlo + per;
  const int total = E + n;
  for (int e = chunk*256 + threadIdx.x; e < total; e += nchunk*256){
    const int d = (e < E) ? ei[E + e] : (e - E);
    if (d >= dlo && d < dhi){
      const int s = (e < E) ? ei[e] : d;
      esrc[atomicAdd(&cursor[d], 1)] = s;
    }
  }
}

// ---------------- k_wprep: merged weight split + folded attention vectors ---
__global__ __launch_bounds__(256) void k_wprep(
    const float* __restrict__ W1, const float* __restrict__ aS1, const float* __restrict__ aD1,
    const float* __restrict__ W2, const float* __restrict__ aS2, const float* __restrict__ aD2,
    unsigned short* __restrict__ W1hi, unsigned short* __restrict__ W1lo,
    unsigned short* __restrict__ W2hi, unsigned short* __restrict__ W2lo,
    float* __restrict__ va1, float* __restrict__ va2)
{
  const int b = blockIdx.x, t = threadIdx.x;
  if (b < 384){
    const float* W = (b < 128) ? W1 : W2;
    unsigned short* hi = (b < 128) ? W1hi : W2hi;
    unsigned short* lo = (b < 128) ? W1lo : W2lo;
    const int idx = ((b < 128) ? b : (b - 128))*256 + t;
    const int k = idx / HIDDIM, n = idx % HIDDIM;
    const float w = W[idx];
    const unsigned short h = bf16_rn(w);
    const unsigned short l = bf16_rn(w - __uint_as_float((unsigned)h << 16));
    const int p = ((k >> 3)*HIDDIM + n)*8 + (k & 7);
    hi[p] = h; lo[p] = l;
  } else {
    if (t < 128){
      #pragma unroll
      for (int h = 0; h < 4; ++h){
        float s = 0.f, d = 0.f;
        for (int k = 0; k < 64; ++k){
          const float w = W1[t*HIDDIM + h*64 + k];
          s = fmaf(w, aS1[h*64 + k], s);
          d = fmaf(w, aD1[h*64 + k], d);
        }
        va1[t*8 + h] = s;
        va1[t*8 + 4 + h] = d;
      }
    } else {
      for (int c = t - 128; c < 256; c += 128){
        float s = 0.f, d = 0.f;
        for (int j = 0; j < 256; ++j){
          const float w = W2[c*HIDDIM + j];
          s = fmaf(w, aS2[j], s);
          d = fmaf(w, aD2[j], d);
        }
        va2[c*2] = s; va2[c*2+1] = d;
      }
    }
  }
}

// ---------------- k_xh_logits: x -> fp16 copy + layer-1 logits --------------
__global__ __launch_bounds__(256) void k_xh_logits(
    const float* __restrict__ X, const float* __restrict__ va1,
    __half* __restrict__ xh, float* __restrict__ as1, float* __restrict__ ad1, int n)
{
  const int lane = threadIdx.x & 63;
  const int node = blockIdx.x*4 + (threadIdx.x >> 6);
  if (node >= n) return;
  const float2 xv = *reinterpret_cast<const float2*>(X + (size_t)node*128 + 2*lane);
  *reinterpret_cast<__half2*>(xh + (size_t)node*128 + 2*lane) = __float22half2_rn(xv);

  const float4 vs0 = *reinterpret_cast<const float4*>(va1 + (2*lane)*8);
  const float4 vd0 = *reinterpret_cast<const float4*>(va1 + (2*lane)*8 + 4);
  const float4 vs1 = *reinterpret_cast<const float4*>(va1 + (2*lane+1)*8);
  const float4 vd1 = *reinterpret_cast<const float4*>(va1 + (2*lane+1)*8 + 4);
  float ps[4], pd[4];
  ps[0] = xv.x*vs0.x + xv.y*vs1.x;  pd[0] = xv.x*vd0.x + xv.y*vd1.x;
  ps[1] = xv.x*vs0.y + xv.y*vs1.y;  pd[1] = xv.x*vd0.y + xv.y*vd1.y;
  ps[2] = xv.x*vs0.z + xv.y*vs1.z;  pd[2] = xv.x*vd0.z + xv.y*vd1.z;
  ps[3] = xv.x*vs0.w + xv.y*vs1.w;  pd[3] = xv.x*vd0.w + xv.y*vd1.w;
  #pragma unroll
  for (int h = 0; h < 4; ++h)
    for (int off = 32; off; off >>= 1){
      ps[h] += __shfl_xor(ps[h], off);
      pd[h] += __shfl_xor(pd[h], off);
    }
  if (lane == 0){
    *reinterpret_cast<float4*>(as1 + (size_t)node*4) = make_float4(ps[0],ps[1],ps[2],ps[3]);
    *reinterpret_cast<float4*>(ad1 + (size_t)node*4) = make_float4(pd[0],pd[1],pd[2],pd[3]);
  }
}

// ---------------- k_prep4: layer-1 weights, 16 lanes per node (avg deg 17) --
__global__ __launch_bounds__(256) void k_prep4(
    const float* __restrict__ as_, const float* __restrict__ ad_,
    const int* __restrict__ offs, const int* __restrict__ esrc,
    __half* __restrict__ p16, float* __restrict__ rdinv, int n)
{
  constexpr float SHIFT = 2.0f;
  const int l4 = threadIdx.x & 15;
  const int node = blockIdx.x*16 + (threadIdx.x >> 4);
  if (node >= n) return;
  const int start = offs[node], end = offs[node+1];

  const float4 adv4 = *reinterpret_cast<const float4*>(ad_ + (size_t)node*4);
  const float adv[4] = {adv4.x, adv4.y, adv4.z, adv4.w};
  float dsum[4] = {0.f, 0.f, 0.f, 0.f};

  for (int e = start + l4; e < end; e += 16){
    const int s = esrc[e];
    const float4 av = *reinterpret_cast<const float4*>(as_ + (size_t)s*4);
    const float a[4] = {av.x, av.y, av.z, av.w};
    union { float2 f; __half2 h2[2]; } o;
    float wq[4];
    #pragma unroll
    for (int h = 0; h < 4; ++h){
      const __half w16 = __float2half(__expf(lrelu(a[h] + adv[h]) - SHIFT));
      wq[h] = __half2float(w16);
      dsum[h] += wq[h];
    }
    o.h2[0] = __half2{__float2half(wq[0]), __float2half(wq[1])};
    o.h2[1] = __half2{__float2half(wq[2]), __float2half(wq[3])};
    *reinterpret_cast<float2*>(&p16[(size_t)4*e]) = o.f;
  }
  #pragma unroll
  for (int h = 0; h < 4; ++h)
    for (int off = 8; off; off >>= 1) dsum[h] += __shfl_xor(dsum[h], off);

  if (l4 == 0){
    *reinterpret_cast<float4*>(rdinv + (size_t)node*4) =
      make_float4(1.f/(dsum[0]+1e-16f), 1.f/(dsum[1]+1e-16f),
                  1.f/(dsum[2]+1e-16f), 1.f/(dsum[3]+1e-16f));
  }
}

// ---------------- k_agg1: gather raw x (fp16), half-wave per node, 8x unroll
__global__ __launch_bounds__(256) void k_agg1(
    const __half* __restrict__ xh, const __half* __restrict__ p16,
    const int* __restrict__ offs, const int* __restrict__ esrc,
    const float* __restrict__ rdinv, unsigned short* __restrict__ xagg, int n)
{
  const int l2 = threadIdx.x & 31;
  const int node = blockIdx.x*8 + (threadIdx.x >> 5);
  if (node >= n) return;
  const int start = offs[node], end = offs[node+1];
  const __half* hp = xh + 4*l2;

  float acc[4][4] = {};   // [head][ch]
  int e = start;
  for (; e + 8 <= end; e += 8){
    int s[8]; float2 pv[8]; float2 xv[8];
    #pragma unroll
    for (int i = 0; i < 8; ++i) s[i] = esrc[e+i];
    #pragma unroll
    for (int i = 0; i < 8; ++i) pv[i] = *reinterpret_cast<const float2*>(p16 + (size_t)4*(e+i));
    #pragma unroll
    for (int i = 0; i < 8; ++i) xv[i] = *reinterpret_cast<const float2*>(hp + (size_t)s[i]*128);
    #pragma unroll
    for (int i = 0; i < 8; ++i){
      union { float2 f; __half2 h2[2]; } ux; ux.f = xv[i];
      const float2 x01 = __half22float2(ux.h2[0]);
      const float2 x23 = __half22float2(ux.h2[1]);
      union { float2 f; __half2 h2[2]; } up; up.f = pv[i];
      const float2 p01 = __half22float2(up.h2[0]);
      const float2 p23 = __half22float2(up.h2[1]);
      const float ph[4] = {p01.x, p01.y, p23.x, p23.y};
      const float xc[4] = {x01.x, x01.y, x23.x, x23.y};
      #pragma unroll
      for (int h = 0; h < 4; ++h)
        #pragma unroll
        for (int c = 0; c < 4; ++c)
          acc[h][c] = fmaf(ph[h], xc[c], acc[h][c]);
    }
  }
  for (; e < end; ++e){
    const int s = esrc[e];
    union { float2 f; __half2 h2[2]; } ux;
    ux.f = *reinterpret_cast<const float2*>(hp + (size_t)s*128);
    const float2 x01 = __half22float2(ux.h2[0]);
    const float2 x23 = __half22float2(ux.h2[1]);
    union { float2 f; __half2 h2[2]; } up;
    up.f = *reinterpret_cast<const float2*>(p16 + (size_t)4*e);
    const float2 p01 = __half22float2(up.h2[0]);
    const float2 p23 = __half22float2(up.h2[1]);
    const float ph[4] = {p01.x, p01.y, p23.x, p23.y};
    const float xc[4] = {x01.x, x01.y, x23.x, x23.y};
    #pragma unroll
    for (int h = 0; h < 4; ++h)
      #pragma unroll
      for (int c = 0; c < 4; ++c)
        acc[h][c] = fmaf(ph[h], xc[c], acc[h][c]);
  }
  const float4 rv = *reinterpret_cast<const float4*>(rdinv + (size_t)node*4);
  const float rd[4] = {rv.x, rv.y, rv.z, rv.w};
  #pragma unroll
  for (int h = 0; h < 4; ++h){
    uint2 pk;
    pk.x = (unsigned)bf16_rn(acc[h][0]*rd[h]) | ((unsigned)bf16_rn(acc[h][1]*rd[h]) << 16);
    pk.y = (unsigned)bf16_rn(acc[h][2]*rd[h]) | ((unsigned)bf16_rn(acc[h][3]*rd[h]) << 16);
    *reinterpret_cast<uint2*>(xagg + (size_t)node*512 + h*128 + 4*l2) = pk;
  }
}

// ---------------- k_gemm1: h1e = ELU(xagg @ blockdiag(W1) + b1) -------------
__global__ __launch_bounds__(256) void k_gemm1(
    const unsigned short* __restrict__ Xagg,
    const unsigned short* __restrict__ Bhi, const unsigned short* __restrict__ Blo,
    const float* __restrict__ b1, const float* __restrict__ va2,
    __half* __restrict__ h1e, float* __restrict__ as2, float* __restrict__ ad2, int M)
{
  __shared__ float lred_s[64][4], lred_d[64][4];
  const int tid = threadIdx.x;
  const int w = tid >> 6, l = tid & 63;
  const int lr = l & 15, lg = l >> 4;
  const int row0 = blockIdx.x*64;
  const int n0 = w*64;
  floatx4 acc[4][4] = {};

  for (int ks = 0; ks < 4; ++ks){
    short8_t a_[4], bh[4], bl[4];
    #pragma unroll
    for (int m = 0; m < 4; ++m){
      const size_t ao = (size_t)(row0 + 16*m + lr)*512 + w*128 + ks*32 + lg*8;
      a_[m] = *reinterpret_cast<const short8_t*>(&Xagg[ao]);
    }
    #pragma unroll
    for (int n = 0; n < 4; ++n){
      const int boff = (((ks*4 + lg)*HIDDIM) + n0 + 16*n + lr)*8;
      bh[n] = *reinterpret_cast<const short8_t*>(&Bhi[boff]);
      bl[n] = *reinterpret_cast<const short8_t*>(&Blo[boff]);
    }
    #pragma unroll
    for (int m = 0; m < 4; ++m)
      #pragma unroll
      for (int n = 0; n < 4; ++n){
        acc[m][n] = __builtin_amdgcn_mfma_f32_16x16x32_bf16(a_[m], bh[n], acc[m][n], 0,0,0);
        acc[m][n] = __builtin_amdgcn_mfma_f32_16x16x32_bf16(a_[m], bl[n], acc[m][n], 0,0,0);
      }
  }

  float bcol[4], v2s[4], v2d[4];
  #pragma unroll
  for (int n = 0; n < 4; ++n){
    const int col = n0 + 16*n + lr;
    bcol[n] = b1[col];
    v2s[n] = va2[col*2];
    v2d[n] = va2[col*2+1];
  }
  #pragma unroll
  for (int m = 0; m < 4; ++m){
    #pragma unroll
    for (int r = 0; r < 4; ++r){
      const int row = row0 + 16*m + lg*4 + r;
      float ps = 0.f, pd = 0.f;
      #pragma unroll
      for (int n = 0; n < 4; ++n){
        float v = acc[m][n][r] + bcol[n];
        v = v > 0.f ? v : __expf(v) - 1.f;           // ELU
        if (row < M) h1e[(size_t)row*HIDDIM + n0 + 16*n + lr] = __float2half(v);
        ps = fmaf(v, v2s[n], ps);
        pd = fmaf(v, v2d[n], pd);
      }
      #pragma unroll
      for (int off = 1; off <= 8; off <<= 1){
        ps += __shfl_xor(ps, off);
        pd += __shfl_xor(pd, off);
      }
      const int rloc = 16*m + lg*4 + r;
      if (lr == 0){ lred_s[rloc][w] = ps; lred_d[rloc][w] = pd; }
    }
  }
  __syncthreads();
  if (tid < 64 && row0 + tid < M){
    as2[row0+tid] = lred_s[tid][0]+lred_s[tid][1]+lred_s[tid][2]+lred_s[tid][3];
    ad2[row0+tid] = lred_d[tid][0]+lred_d[tid][1]+lred_d[tid][2]+lred_d[tid][3];
  }
}

// ---------------- k_agg2: fused softmax + gather (layer 2) ------------------
__global__ __launch_bounds__(256) void k_agg2(
    const __half* __restrict__ Hs,
    const float* __restrict__ as2, const float* __restrict__ ad2,
    const int* __restrict__ offs, const int* __restrict__ esrc,
    unsigned short* __restrict__ xagg2, int n)
{
  constexpr float SHIFT = 4.0f;
  const int lane = threadIdx.x & 63;
  const int node = blockIdx.x*4 + (threadIdx.x >> 6);
  if (node >= n) return;
  const int start = offs[node], end = offs[node+1];
  const float adn = ad2[node];
  const __half* hp = Hs + 4*lane;

  float4 a0 = {0,0,0,0}, a1 = {0,0,0,0}, a2 = {0,0,0,0}, a3 = {0,0,0,0};
  float dsum = 0.f;
  int e = start;
  for (; e + 4 <= end; e += 4){
    const int s0 = esrc[e+0], s1 = esrc[e+1], s2 = esrc[e+2], s3 = esrc[e+3];
    const float w0 = __expf(lrelu(as2[s0] + adn) - SHIFT);
    const float w1 = __expf(lrelu(as2[s1] + adn) - SHIFT);
    const float w2 = __expf(lrelu(as2[s2] + adn) - SHIFT);
    const float w3 = __expf(lrelu(as2[s3] + adn) - SHIFT);
    dsum += (w0 + w1) + (w2 + w3);
    const float4 h0 = ldh4(hp + (size_t)s0*HIDDIM);
    const float4 h1 = ldh4(hp + (size_t)s1*HIDDIM);
    const float4 h2 = ldh4(hp + (size_t)s2*HIDDIM);
    const float4 h3 = ldh4(hp + (size_t)s3*HIDDIM);
    a0.x = fmaf(w0, h0.x, a0.x); a0.y = fmaf(w0, h0.y, a0.y);
    a0.z = fmaf(w0, h0.z, a0.z); a0.w = fmaf(w0, h0.w, a0.w);
    a1.x = fmaf(w1, h1.x, a1.x); a1.y = fmaf(w1, h1.y, a1.y);
    a1.z = fmaf(w1, h1.z, a1.z); a1.w = fmaf(w1, h1.w, a1.w);
    a2.x = fmaf(w2, h2.x, a2.x); a2.y = fmaf(w2, h2.y, a2.y);
    a2.z = fmaf(w2, h2.z, a2.z); a2.w = fmaf(w2, h2.w, a2.w);
    a3.x = fmaf(w3, h3.x, a3.x); a3.y = fmaf(w3, h3.y, a3.y);
    a3.z = fmaf(w3, h3.z, a3.z); a3.w = fmaf(w3, h3.w, a3.w);
  }
  for (; e < end; ++e){
    const int s = esrc[e];
    const float w = __expf(lrelu(as2[s] + adn) - SHIFT);
    dsum += w;
    const float4 hv = ldh4(hp + (size_t)s*HIDDIM);
    a0.x = fmaf(w, hv.x, a0.x); a0.y = fmaf(w, hv.y, a0.y);
    a0.z = fmaf(w, hv.z, a0.z); a0.w = fmaf(w, hv.w, a0.w);
  }
  const float rd = 1.f/(dsum + 1e-16f);
  float4 acc;
  acc.x = ((a0.x + a1.x) + (a2.x + a3.x)) * rd;
  acc.y = ((a0.y + a1.y) + (a2.y + a3.y)) * rd;
  acc.z = ((a0.z + a1.z) + (a2.z + a3.z)) * rd;
  acc.w = ((a0.w + a1.w) + (a2.w + a3.w)) * rd;

  uint2 pk;
  pk.x = (unsigned)bf16_rn(acc.x) | ((unsigned)bf16_rn(acc.y) << 16);
  pk.y = (unsigned)bf16_rn(acc.z) | ((unsigned)bf16_rn(acc.w) << 16);
  *reinterpret_cast<uint2*>(xagg2 + (size_t)node*HIDDIM + 4*lane) = pk;
}

// ---------------- k_gemm2: out = xagg2 @ W2 + b2 ----------------------------
__global__ __launch_bounds__(256) void k_gemm2(
    const unsigned short* __restrict__ Xagg2,
    const unsigned short* __restrict__ Bhi, const unsigned short* __restrict__ Blo,
    const float* __restrict__ b2, float* __restrict__ Out, int M)
{
  const int tid = threadIdx.x;
  const int w = tid >> 6, l = tid & 63;
  const int lr = l & 15, lg = l >> 4;
  const int row0 = blockIdx.x*64;
  const int n0 = w*64;
  floatx4 acc[4][4] = {};

  for (int ks = 0; ks < 8; ++ks){
    short8_t a_[4], bh[4], bl[4];
    #pragma unroll
    for (int m = 0; m < 4; ++m){
      const size_t ao = (size_t)(row0 + 16*m + lr)*HIDDIM + ks*32 + lg*8;
      a_[m] = *reinterpret_cast<const short8_t*>(&Xagg2[ao]);
    }
    #pragma unroll
    for (int n = 0; n < 4; ++n){
      const int boff = (((ks*4 + lg)*HIDDIM) + n0 + 16*n + lr)*8;
      bh[n] = *reinterpret_cast<const short8_t*>(&Bhi[boff]);
      bl[n] = *reinterpret_cast<const short8_t*>(&Blo[boff]);
    }
    #pragma unroll
    for (int m = 0; m < 4; ++m)
      #pragma unroll
      for (int n = 0; n < 4; ++n){
        acc[m][n] = __builtin_amdgcn_mfma_f32_16x16x32_bf16(a_[m], bh[n], acc[m][n], 0,0,0);
        acc[m][n] = __builtin_amdgcn_mfma_f32_16x16x32_bf16(a_[m], bl[n], acc[m][n], 0,0,0);
      }
  }

  float bcol[4];
  #pragma unroll
  for (int n = 0; n < 4; ++n) bcol[n] = b2[n0 + 16*n + lr];
  #pragma unroll
  for (int m = 0; m < 4; ++m){
    #pragma unroll
    for (int r = 0; r < 4; ++r){
      const int row = row0 + 16*m + lg*4 + r;
      if (row < M){
        #pragma unroll
        for (int n = 0; n < 4; ++n)
          Out[(size_t)row*HIDDIM + n0 + 16*n + lr] = acc[m][n][r] + bcol[n];
      }
    }
  }
}

// ---------------- launch ----------------
extern "C" void kernel_launch(void* const* d_in, const int* in_sizes, int n_in,
                              void* d_out, int out_size, void* d_ws, size_t ws_size,
                              hipStream_t stream)
{
  const float* x    = (const float*)d_in[0];
  const int*   ei   = (const int*)  d_in[1];
  const float* W1   = (const float*)d_in[2];
  const float* aS1  = (const float*)d_in[3];
  const float* aD1  = (const float*)d_in[4];
  const float* b1   = (const float*)d_in[5];
  const float* W2   = (const float*)d_in[6];
  const float* aS2  = (const float*)d_in[7];
  const float* aD2  = (const float*)d_in[8];
  const float* b2   = (const float*)d_in[9];
  float* out = (float*)d_out;

  char* ws = (char*)d_ws;
  size_t off = 0;
  auto alloc = [&](size_t bytes){ void* p = ws + off; off += (bytes + 255) & ~255ull; return p; };

  unsigned short* xagg  = (unsigned short*)alloc((size_t)NT64*512*sizeof(short)); // 51.2 MB
  __half*         h1e   = (__half*)alloc((size_t)NT64*HIDDIM*sizeof(__half));     // 25.6 MB
  unsigned short* xagg2 = (unsigned short*)alloc((size_t)NT64*HIDDIM*sizeof(short)); // 25.6 MB
  __half*         xh    = (__half*)xagg2;   // alias: xh dead before xagg2 written
  __half* p16   = (__half*)alloc((size_t)4*EN*sizeof(__half));          // 6.8 MB
  float* as1    = (float*)alloc((size_t)NNODES*4*sizeof(float));
  float* ad1    = (float*)alloc((size_t)NNODES*4*sizeof(float));
  float* rdinv1 = (float*)alloc((size_t)NNODES*4*sizeof(float));
  float* as2    = (float*)alloc((size_t)NNODES*sizeof(float));
  float* ad2    = (float*)alloc((size_t)NNODES*sizeof(float));
  float* va1    = (float*)alloc(128*8*sizeof(float));
  float* va2    = (float*)alloc(256*2*sizeof(float));
  unsigned short* W1hi = (unsigned short*)alloc((size_t)128*HIDDIM*sizeof(short));
  unsigned short* W1lo = (unsigned short*)alloc((size_t)128*HIDDIM*sizeof(short));
  unsigned short* W2hi = (unsigned short*)alloc((size_t)256*HIDDIM*sizeof(short));
  unsigned short* W2lo = (unsigned short*)alloc((size_t)256*HIDDIM*sizeof(short));
  int*   counts = (int*)alloc((size_t)NNODES*sizeof(int));
  int*   offs   = (int*)alloc((size_t)(NNODES+1)*sizeof(int));
  int*   cursor = (int*)alloc((size_t)NNODES*sizeof(int));
  int*   bsum   = (int*)alloc(64*sizeof(int));
  int*   boff   = (int*)alloc(64*sizeof(int));
  int*   esrc   = (int*)alloc((size_t)EN*sizeof(int));

  const int nscan = (NNODES + SCAN_CHUNK - 1)/SCAN_CHUNK;   // 25
  const int node_grid = (NNODES + 3)/4;                     // 12500

  // CSR by dst (partitioned count + scatter; implicit self-loop via +1 in scans)
  hipMemsetAsync(counts, 0, (size_t)NNODES*sizeof(int), stream);
  k_count     <<<NPART*120, 256, 0, stream>>>(ei, counts, NEDGES, NNODES);
  k_scan_a    <<<nscan, 256, 0, stream>>>(counts, bsum, NNODES);
  k_scan_b    <<<1, 64, 0, stream>>>(bsum, boff, offs, nscan, NNODES);
  k_scan_c    <<<nscan, 256, 0, stream>>>(counts, boff, offs, cursor, NNODES);
  k_scatter   <<<NPART*120, 256, 0, stream>>>(ei, cursor, esrc, NEDGES, NNODES);

  // weight prep (merged) + x fp16 copy / layer-1 logits
  k_wprep<<<385, 256, 0, stream>>>(W1, aS1, aD1, W2, aS2, aD2,
                                   W1hi, W1lo, W2hi, W2lo, va1, va2);
  k_xh_logits<<<node_grid, 256, 0, stream>>>(x, va1, xh, as1, ad1, NNODES);

  // layer 1: 16-lane prep -> aggregate raw x -> transform (+ layer-2 logits)
  k_prep4<<<(NNODES+15)/16, 256, 0, stream>>>(as1, ad1, offs, esrc, p16, rdinv1, NNODES);
  k_agg1<<<(NNODES+7)/8, 256, 0, stream>>>(xh, p16, offs, esrc, rdinv1, xagg, NNODES);
  k_gemm1<<<NTILES, 256, 0, stream>>>(xagg, W1hi, W1lo, b1, va2, h1e, as2, ad2, NNODES);

  // layer 2: FUSED softmax+aggregate -> transform
  k_agg2<<<node_grid, 256, 0, stream>>>(h1e, as2, ad2, offs, esrc, xagg2, NNODES);
  k_gemm2<<<NTILES, 256, 0, stream>>>(xagg2, W2hi, W2lo, b2, out, NNODES);
}

// Round 15
// 310.949 us; speedup vs baseline: 1.0672x; 1.0375x over previous
//
#include <hip/hip_runtime.h>
#include <hip/hip_fp16.h>

#define NNODES 50000
#define NEDGES 800000
#define HIDDIM 256
#define EN (NEDGES + NNODES)          // CSR entries incl. self-loops
#define NTILES ((NNODES + 63)/64)     // 782 row-tiles of 64
#define NT64 (NTILES*64)              // padded row count 50048
#define NPART 8                       // dst-partitions (XCD count)
#define CNT_BLOCKS (NPART*120)        // 960 count blocks
#define WPREP_BLOCKS 385
#define SCANA_BLOCKS 25

constexpr float NEG = 0.2f;

typedef __attribute__((ext_vector_type(8))) short short8_t;   // bf16x8 MFMA frag
typedef __attribute__((ext_vector_type(4))) float floatx4;    // f32x4 acc

__device__ __forceinline__ float lrelu(float v){ return v >= 0.f ? v : NEG*v; }

__device__ __forceinline__ unsigned short bf16_rn(float x){
  unsigned u = __float_as_uint(x);
  return (unsigned short)((u + 0x7FFFu + ((u >> 16) & 1u)) >> 16);
}

__device__ __forceinline__ float4 ldh4(const __half* p){
  union { float2 f; __half2 h[2]; } u;
  u.f = *reinterpret_cast<const float2*>(p);
  const float2 lo = __half22float2(u.h[0]);
  const float2 hi = __half22float2(u.h[1]);
  return make_float4(lo.x, lo.y, hi.x, hi.y);
}

// ---------------- k_pre1: dst-partitioned count  ∥  weight prep --------------
// blocks [0,CNT_BLOCKS): edge count by dst (XCD-local atomics, R9 lesson)
// blocks [CNT_BLOCKS, +384): W1/W2 split to bf16 hi/lo fragment layout
// block CNT_BLOCKS+384: folded attention vectors va1/va2
__global__ __launch_bounds__(256) void k_pre1(
    const int* __restrict__ ei, int* counts, int E, int n,
    const float* __restrict__ W1, const float* __restrict__ aS1, const float* __restrict__ aD1,
    const float* __restrict__ W2, const float* __restrict__ aS2, const float* __restrict__ aD2,
    unsigned short* __restrict__ W1hi, unsigned short* __restrict__ W1lo,
    unsigned short* __restrict__ W2hi, unsigned short* __restrict__ W2lo,
    float* __restrict__ va1, float* __restrict__ va2)
{
  const int t = threadIdx.x;
  if (blockIdx.x < CNT_BLOCKS){
    const int part = blockIdx.x & (NPART-1);
    const int nchunk = CNT_BLOCKS >> 3;
    const int chunk = blockIdx.x >> 3;
    const int per = n / NPART;
    const int dlo = part*per, dhi = dlo + per;
    for (int e = chunk*256 + t; e < E; e += nchunk*256){
      const int d = ei[E + e];
      if (d >= dlo && d < dhi) atomicAdd(&counts[d], 1);
    }
    return;
  }
  const int b = blockIdx.x - CNT_BLOCKS;
  if (b < 384){
    const float* W = (b < 128) ? W1 : W2;
    unsigned short* hi = (b < 128) ? W1hi : W2hi;
    unsigned short* lo = (b < 128) ? W1lo : W2lo;
    const int idx = ((b < 128) ? b : (b - 128))*256 + t;
    const int k = idx / HIDDIM, nn = idx % HIDDIM;
    const float w = W[idx];
    const unsigned short h = bf16_rn(w);
    const unsigned short l = bf16_rn(w - __uint_as_float((unsigned)h << 16));
    const int p = ((k >> 3)*HIDDIM + nn)*8 + (k & 7);
    hi[p] = h; lo[p] = l;
  } else {
    if (t < 128){
      #pragma unroll
      for (int h = 0; h < 4; ++h){
        float s = 0.f, d = 0.f;
        for (int k = 0; k < 64; ++k){
          const float w = W1[t*HIDDIM + h*64 + k];
          s = fmaf(w, aS1[h*64 + k], s);
          d = fmaf(w, aD1[h*64 + k], d);
        }
        va1[t*8 + h] = s;
        va1[t*8 + 4 + h] = d;
      }
    } else {
      for (int c = t - 128; c < 256; c += 128){
        float s = 0.f, d = 0.f;
        for (int j = 0; j < 256; ++j){
          const float w = W2[c*HIDDIM + j];
          s = fmaf(w, aS2[j], s);
          d = fmaf(w, aD2[j], d);
        }
        va2[c*2] = s; va2[c*2+1] = d;
      }
    }
  }
}

#define SCAN_CHUNK 2048
// ---------------- k_pre2: scan_a (block sums)  ∥  xh_logits ------------------
__global__ __launch_bounds__(256) void k_pre2(
    const int* __restrict__ counts, int* __restrict__ bsum, int n,
    const float* __restrict__ X, const float* __restrict__ va1,
    __half* __restrict__ xh, float* __restrict__ as1, float* __restrict__ ad1)
{
  const int t = threadIdx.x;
  if (blockIdx.x < SCANA_BLOCKS){
    __shared__ int ws[4];
    const int idx0 = blockIdx.x*SCAN_CHUNK + t*8;
    int s = 0;
    #pragma unroll
    for (int i = 0; i < 8; ++i) if (idx0 + i < n) s += counts[idx0 + i] + 1;
    for (int off = 32; off; off >>= 1) s += __shfl_xor(s, off);
    if ((t & 63) == 0) ws[t >> 6] = s;
    __syncthreads();
    if (t == 0) bsum[blockIdx.x] = ws[0] + ws[1] + ws[2] + ws[3];
    return;
  }
  const int lane = t & 63;
  const int node = (blockIdx.x - SCANA_BLOCKS)*4 + (t >> 6);
  if (node >= n) return;
  const float2 xv = *reinterpret_cast<const float2*>(X + (size_t)node*128 + 2*lane);
  *reinterpret_cast<__half2*>(xh + (size_t)node*128 + 2*lane) = __float22half2_rn(xv);

  const float4 vs0 = *reinterpret_cast<const float4*>(va1 + (2*lane)*8);
  const float4 vd0 = *reinterpret_cast<const float4*>(va1 + (2*lane)*8 + 4);
  const float4 vs1 = *reinterpret_cast<const float4*>(va1 + (2*lane+1)*8);
  const float4 vd1 = *reinterpret_cast<const float4*>(va1 + (2*lane+1)*8 + 4);
  float ps[4], pd[4];
  ps[0] = xv.x*vs0.x + xv.y*vs1.x;  pd[0] = xv.x*vd0.x + xv.y*vd1.x;
  ps[1] = xv.x*vs0.y + xv.y*vs1.y;  pd[1] = xv.x*vd0.y + xv.y*vd1.y;
  ps[2] = xv.x*vs0.z + xv.y*vs1.z;  pd[2] = xv.x*vd0.z + xv.y*vd1.z;
  ps[3] = xv.x*vs0.w + xv.y*vs1.w;  pd[3] = xv.x*vd0.w + xv.y*vd1.w;
  #pragma unroll
  for (int h = 0; h < 4; ++h)
    for (int off = 32; off; off >>= 1){
      ps[h] += __shfl_xor(ps[h], off);
      pd[h] += __shfl_xor(pd[h], off);
    }
  if (lane == 0){
    *reinterpret_cast<float4*>(as1 + (size_t)node*4) = make_float4(ps[0],ps[1],ps[2],ps[3]);
    *reinterpret_cast<float4*>(ad1 + (size_t)node*4) = make_float4(pd[0],pd[1],pd[2],pd[3]);
  }
}

__global__ void k_scan_b(const int* __restrict__ bsum, int* __restrict__ boff,
                         int* __restrict__ offs, int nb, int n){
  if (threadIdx.x == 0){
    int run = 0;
    for (int i = 0; i < nb; ++i){ boff[i] = run; run += bsum[i]; }
    offs[n] = run;
  }
}
__global__ __launch_bounds__(256) void k_scan_c(const int* __restrict__ counts,
                                                const int* __restrict__ boff,
                                                int* __restrict__ offs,
                                                int* __restrict__ cursor, int n){
  __shared__ int sc[256];
  const int t = threadIdx.x;
  const int idx0 = blockIdx.x*SCAN_CHUNK + t*8;
  int v[8], pre[8], s = 0;
  #pragma unroll
  for (int i = 0; i < 8; ++i){
    v[i] = (idx0 + i < n) ? counts[idx0 + i] + 1 : 0;
    pre[i] = s; s += v[i];
  }
  sc[t] = s;
  __syncthreads();
  int run = s;
  for (int off = 1; off < 256; off <<= 1){
    int add = (t >= off) ? sc[t - off] : 0;
    __syncthreads();
    sc[t] += add;
    __syncthreads();
  }
  const int excl = sc[t] - run;
  const int toff = boff[blockIdx.x] + excl;
  #pragma unroll
  for (int i = 0; i < 8; ++i){
    if (idx0 + i < n){
      const int o = toff + pre[i];
      offs[idx0 + i] = o;
      cursor[idx0 + i] = o;
    }
  }
}

// dst-partitioned scatter (R9: kills write-allocate amplification)
__global__ __launch_bounds__(256) void k_scatter(const int* __restrict__ ei, int* cursor,
                          int* __restrict__ esrc, int E, int n){
  const int part = blockIdx.x & (NPART-1);
  const int nchunk = gridDim.x >> 3;
  const int chunk = blockIdx.x >> 3;
  const int per = n / NPART;
  const int dlo = part*per, dhi = dlo + per;
  const int total = E + n;
  for (int e = chunk*256 + threadIdx.x; e < total; e += nchunk*256){
    const int d = (e < E) ? ei[E + e] : (e - E);
    if (d >= dlo && d < dhi){
      const int s = (e < E) ? ei[e] : d;
      esrc[atomicAdd(&cursor[d], 1)] = s;
    }
  }
}

// ---------------- k_prep4: layer-1 weights, 16 lanes per node (avg deg 17) --
__global__ __launch_bounds__(256) void k_prep4(
    const float* __restrict__ as_, const float* __restrict__ ad_,
    const int* __restrict__ offs, const int* __restrict__ esrc,
    __half* __restrict__ p16, float* __restrict__ rdinv, int n)
{
  constexpr float SHIFT = 2.0f;
  const int l4 = threadIdx.x & 15;
  const int node = blockIdx.x*16 + (threadIdx.x >> 4);
  if (node >= n) return;
  const int start = offs[node], end = offs[node+1];

  const float4 adv4 = *reinterpret_cast<const float4*>(ad_ + (size_t)node*4);
  const float adv[4] = {adv4.x, adv4.y, adv4.z, adv4.w};
  float dsum[4] = {0.f, 0.f, 0.f, 0.f};

  for (int e = start + l4; e < end; e += 16){
    const int s = esrc[e];
    const float4 av = *reinterpret_cast<const float4*>(as_ + (size_t)s*4);
    const float a[4] = {av.x, av.y, av.z, av.w};
    union { float2 f; __half2 h2[2]; } o;
    float wq[4];
    #pragma unroll
    for (int h = 0; h < 4; ++h){
      const __half w16 = __float2half(__expf(lrelu(a[h] + adv[h]) - SHIFT));
      wq[h] = __half2float(w16);
      dsum[h] += wq[h];
    }
    o.h2[0] = __half2{__float2half(wq[0]), __float2half(wq[1])};
    o.h2[1] = __half2{__float2half(wq[2]), __float2half(wq[3])};
    *reinterpret_cast<float2*>(&p16[(size_t)4*e]) = o.f;
  }
  #pragma unroll
  for (int h = 0; h < 4; ++h)
    for (int off = 8; off; off >>= 1) dsum[h] += __shfl_xor(dsum[h], off);

  if (l4 == 0){
    *reinterpret_cast<float4*>(rdinv + (size_t)node*4) =
      make_float4(1.f/(dsum[0]+1e-16f), 1.f/(dsum[1]+1e-16f),
                  1.f/(dsum[2]+1e-16f), 1.f/(dsum[3]+1e-16f));
  }
}

// ---------------- k_agg1: gather raw x (fp16), half-wave per node, 8x unroll
__global__ __launch_bounds__(256) void k_agg1(
    const __half* __restrict__ xh, const __half* __restrict__ p16,
    const int* __restrict__ offs, const int* __restrict__ esrc,
    const float* __restrict__ rdinv, unsigned short* __restrict__ xagg, int n)
{
  const int l2 = threadIdx.x & 31;
  const int node = blockIdx.x*8 + (threadIdx.x >> 5);
  if (node >= n) return;
  const int start = offs[node], end = offs[node+1];
  const __half* hp = xh + 4*l2;

  float acc[4][4] = {};   // [head][ch]
  int e = start;
  for (; e + 8 <= end; e += 8){
    int s[8]; float2 pv[8]; float2 xv[8];
    #pragma unroll
    for (int i = 0; i < 8; ++i) s[i] = esrc[e+i];
    #pragma unroll
    for (int i = 0; i < 8; ++i) pv[i] = *reinterpret_cast<const float2*>(p16 + (size_t)4*(e+i));
    #pragma unroll
    for (int i = 0; i < 8; ++i) xv[i] = *reinterpret_cast<const float2*>(hp + (size_t)s[i]*128);
    #pragma unroll
    for (int i = 0; i < 8; ++i){
      union { float2 f; __half2 h2[2]; } ux; ux.f = xv[i];
      const float2 x01 = __half22float2(ux.h2[0]);
      const float2 x23 = __half22float2(ux.h2[1]);
      union { float2 f; __half2 h2[2]; } up; up.f = pv[i];
      const float2 p01 = __half22float2(up.h2[0]);
      const float2 p23 = __half22float2(up.h2[1]);
      const float ph[4] = {p01.x, p01.y, p23.x, p23.y};
      const float xc[4] = {x01.x, x01.y, x23.x, x23.y};
      #pragma unroll
      for (int h = 0; h < 4; ++h)
        #pragma unroll
        for (int c = 0; c < 4; ++c)
          acc[h][c] = fmaf(ph[h], xc[c], acc[h][c]);
    }
  }
  for (; e < end; ++e){
    const int s = esrc[e];
    union { float2 f; __half2 h2[2]; } ux;
    ux.f = *reinterpret_cast<const float2*>(hp + (size_t)s*128);
    const float2 x01 = __half22float2(ux.h2[0]);
    const float2 x23 = __half22float2(ux.h2[1]);
    union { float2 f; __half2 h2[2]; } up;
    up.f = *reinterpret_cast<const float2*>(p16 + (size_t)4*e);
    const float2 p01 = __half22float2(up.h2[0]);
    const float2 p23 = __half22float2(up.h2[1]);
    const float ph[4] = {p01.x, p01.y, p23.x, p23.y};
    const float xc[4] = {x01.x, x01.y, x23.x, x23.y};
    #pragma unroll
    for (int h = 0; h < 4; ++h)
      #pragma unroll
      for (int c = 0; c < 4; ++c)
        acc[h][c] = fmaf(ph[h], xc[c], acc[h][c]);
  }
  const float4 rv = *reinterpret_cast<const float4*>(rdinv + (size_t)node*4);
  const float rd[4] = {rv.x, rv.y, rv.z, rv.w};
  #pragma unroll
  for (int h = 0; h < 4; ++h){
    uint2 pk;
    pk.x = (unsigned)bf16_rn(acc[h][0]*rd[h]) | ((unsigned)bf16_rn(acc[h][1]*rd[h]) << 16);
    pk.y = (unsigned)bf16_rn(acc[h][2]*rd[h]) | ((unsigned)bf16_rn(acc[h][3]*rd[h]) << 16);
    *reinterpret_cast<uint2*>(xagg + (size_t)node*512 + h*128 + 4*l2) = pk;
  }
}

// ---------------- k_gemm1: h1e = ELU(xagg @ blockdiag(W1) + b1) -------------
__global__ __launch_bounds__(256) void k_gemm1(
    const unsigned short* __restrict__ Xagg,
    const unsigned short* __restrict__ Bhi, const unsigned short* __restrict__ Blo,
    const float* __restrict__ b1, const float* __restrict__ va2,
    __half* __restrict__ h1e, float* __restrict__ as2, float* __restrict__ ad2, int M)
{
  __shared__ float lred_s[64][4], lred_d[64][4];
  const int tid = threadIdx.x;
  const int w = tid >> 6, l = tid & 63;
  const int lr = l & 15, lg = l >> 4;
  const int row0 = blockIdx.x*64;
  const int n0 = w*64;
  floatx4 acc[4][4] = {};

  for (int ks = 0; ks < 4; ++ks){
    short8_t a_[4], bh[4], bl[4];
    #pragma unroll
    for (int m = 0; m < 4; ++m){
      const size_t ao = (size_t)(row0 + 16*m + lr)*512 + w*128 + ks*32 + lg*8;
      a_[m] = *reinterpret_cast<const short8_t*>(&Xagg[ao]);
    }
    #pragma unroll
    for (int n = 0; n < 4; ++n){
      const int boff = (((ks*4 + lg)*HIDDIM) + n0 + 16*n + lr)*8;
      bh[n] = *reinterpret_cast<const short8_t*>(&Bhi[boff]);
      bl[n] = *reinterpret_cast<const short8_t*>(&Blo[boff]);
    }
    #pragma unroll
    for (int m = 0; m < 4; ++m)
      #pragma unroll
      for (int n = 0; n < 4; ++n){
        acc[m][n] = __builtin_amdgcn_mfma_f32_16x16x32_bf16(a_[m], bh[n], acc[m][n], 0,0,0);
        acc[m][n] = __builtin_amdgcn_mfma_f32_16x16x32_bf16(a_[m], bl[n], acc[m][n], 0,0,0);
      }
  }

  float bcol[4], v2s[4], v2d[4];
  #pragma unroll
  for (int n = 0; n < 4; ++n){
    const int col = n0 + 16*n + lr;
    bcol[n] = b1[col];
    v2s[n] = va2[col*2];
    v2d[n] = va2[col*2+1];
  }
  #pragma unroll
  for (int m = 0; m < 4; ++m){
    #pragma unroll
    for (int r = 0; r < 4; ++r){
      const int row = row0 + 16*m + lg*4 + r;
      float ps = 0.f, pd = 0.f;
      #pragma unroll
      for (int n = 0; n < 4; ++n){
        float v = acc[m][n][r] + bcol[n];
        v = v > 0.f ? v : __expf(v) - 1.f;           // ELU
        if (row < M) h1e[(size_t)row*HIDDIM + n0 + 16*n + lr] = __float2half(v);
        ps = fmaf(v, v2s[n], ps);
        pd = fmaf(v, v2d[n], pd);
      }
      #pragma unroll
      for (int off = 1; off <= 8; off <<= 1){
        ps += __shfl_xor(ps, off);
        pd += __shfl_xor(pd, off);
      }
      const int rloc = 16*m + lg*4 + r;
      if (lr == 0){ lred_s[rloc][w] = ps; lred_d[rloc][w] = pd; }
    }
  }
  __syncthreads();
  if (tid < 64 && row0 + tid < M){
    as2[row0+tid] = lred_s[tid][0]+lred_s[tid][1]+lred_s[tid][2]+lred_s[tid][3];
    ad2[row0+tid] = lred_d[tid][0]+lred_d[tid][1]+lred_d[tid][2]+lred_d[tid][3];
  }
}

// ---------------- k_agg2: fused softmax + gather (layer 2) ------------------
__global__ __launch_bounds__(256) void k_agg2(
    const __half* __restrict__ Hs,
    const float* __restrict__ as2, const float* __restrict__ ad2,
    const int* __restrict__ offs, const int* __restrict__ esrc,
    unsigned short* __restrict__ xagg2, int n)
{
  constexpr float SHIFT = 4.0f;
  const int lane = threadIdx.x & 63;
  const int node = blockIdx.x*4 + (threadIdx.x >> 6);
  if (node >= n) return;
  const int start = offs[node], end = offs[node+1];
  const float adn = ad2[node];
  const __half* hp = Hs + 4*lane;

  float4 a0 = {0,0,0,0}, a1 = {0,0,0,0}, a2 = {0,0,0,0}, a3 = {0,0,0,0};
  float dsum = 0.f;
  int e = start;
  for (; e + 4 <= end; e += 4){
    const int s0 = esrc[e+0], s1 = esrc[e+1], s2 = esrc[e+2], s3 = esrc[e+3];
    const float w0 = __expf(lrelu(as2[s0] + adn) - SHIFT);
    const float w1 = __expf(lrelu(as2[s1] + adn) - SHIFT);
    const float w2 = __expf(lrelu(as2[s2] + adn) - SHIFT);
    const float w3 = __expf(lrelu(as2[s3] + adn) - SHIFT);
    dsum += (w0 + w1) + (w2 + w3);
    const float4 h0 = ldh4(hp + (size_t)s0*HIDDIM);
    const float4 h1 = ldh4(hp + (size_t)s1*HIDDIM);
    const float4 h2 = ldh4(hp + (size_t)s2*HIDDIM);
    const float4 h3 = ldh4(hp + (size_t)s3*HIDDIM);
    a0.x = fmaf(w0, h0.x, a0.x); a0.y = fmaf(w0, h0.y, a0.y);
    a0.z = fmaf(w0, h0.z, a0.z); a0.w = fmaf(w0, h0.w, a0.w);
    a1.x = fmaf(w1, h1.x, a1.x); a1.y = fmaf(w1, h1.y, a1.y);
    a1.z = fmaf(w1, h1.z, a1.z); a1.w = fmaf(w1, h1.w, a1.w);
    a2.x = fmaf(w2, h2.x, a2.x); a2.y = fmaf(w2, h2.y, a2.y);
    a2.z = fmaf(w2, h2.z, a2.z); a2.w = fmaf(w2, h2.w, a2.w);
    a3.x = fmaf(w3, h3.x, a3.x); a3.y = fmaf(w3, h3.y, a3.y);
    a3.z = fmaf(w3, h3.z, a3.z); a3.w = fmaf(w3, h3.w, a3.w);
  }
  for (; e < end; ++e){
    const int s = esrc[e];
    const float w = __expf(lrelu(as2[s] + adn) - SHIFT);
    dsum += w;
    const float4 hv = ldh4(hp + (size_t)s*HIDDIM);
    a0.x = fmaf(w, hv.x, a0.x); a0.y = fmaf(w, hv.y, a0.y);
    a0.z = fmaf(w, hv.z, a0.z); a0.w = fmaf(w, hv.w, a0.w);
  }
  const float rd = 1.f/(dsum + 1e-16f);
  float4 acc;
  acc.x = ((a0.x + a1.x) + (a2.x + a3.x)) * rd;
  acc.y = ((a0.y + a1.y) + (a2.y + a3.y)) * rd;
  acc.z = ((a0.z + a1.z) + (a2.z + a3.z)) * rd;
  acc.w = ((a0.w + a1.w) + (a2.w + a3.w)) * rd;

  uint2 pk;
  pk.x = (unsigned)bf16_rn(acc.x) | ((unsigned)bf16_rn(acc.y) << 16);
  pk.y = (unsigned)bf16_rn(acc.z) | ((unsigned)bf16_rn(acc.w) << 16);
  *reinterpret_cast<uint2*>(xagg2 + (size_t)node*HIDDIM + 4*lane) = pk;
}

// ---------------- k_gemm2: out = xagg2 @ W2 + b2 ----------------------------
__global__ __launch_bounds__(256) void k_gemm2(
    const unsigned short* __restrict__ Xagg2,
    const unsigned short* __restrict__ Bhi, const unsigned short* __restrict__ Blo,
    const float* __restrict__ b2, float* __restrict__ Out, int M)
{
  const int tid = threadIdx.x;
  const int w = tid >> 6, l = tid & 63;
  const int lr = l & 15, lg = l >> 4;
  const int row0 = blockIdx.x*64;
  const int n0 = w*64;
  floatx4 acc[4][4] = {};

  for (int ks = 0; ks < 8; ++ks){
    short8_t a_[4], bh[4], bl[4];
    #pragma unroll
    for (int m = 0; m < 4; ++m){
      const size_t ao = (size_t)(row0 + 16*m + lr)*HIDDIM + ks*32 + lg*8;
      a_[m] = *reinterpret_cast<const short8_t*>(&Xagg2[ao]);
    }
    #pragma unroll
    for (int n = 0; n < 4; ++n){
      const int boff = (((ks*4 + lg)*HIDDIM) + n0 + 16*n + lr)*8;
      bh[n] = *reinterpret_cast<const short8_t*>(&Bhi[boff]);
      bl[n] = *reinterpret_cast<const short8_t*>(&Blo[boff]);
    }
    #pragma unroll
    for (int m = 0; m < 4; ++m)
      #pragma unroll
      for (int n = 0; n < 4; ++n){
        acc[m][n] = __builtin_amdgcn_mfma_f32_16x16x32_bf16(a_[m], bh[n], acc[m][n], 0,0,0);
        acc[m][n] = __builtin_amdgcn_mfma_f32_16x16x32_bf16(a_[m], bl[n], acc[m][n], 0,0,0);
      }
  }

  float bcol[4];
  #pragma unroll
  for (int n = 0; n < 4; ++n) bcol[n] = b2[n0 + 16*n + lr];
  #pragma unroll
  for (int m = 0; m < 4; ++m){
    #pragma unroll
    for (int r = 0; r < 4; ++r){
      const int row = row0 + 16*m + lg*4 + r;
      if (row < M){
        #pragma unroll
        for (int n = 0; n < 4; ++n)
          Out[(size_t)row*HIDDIM + n0 + 16*n + lr] = acc[m][n][r] + bcol[n];
      }
    }
  }
}

// ---------------- launch ----------------
extern "C" void kernel_launch(void* const* d_in, const int* in_sizes, int n_in,
                              void* d_out, int out_size, void* d_ws, size_t ws_size,
                              hipStream_t stream)
{
  const float* x    = (const float*)d_in[0];
  const int*   ei   = (const int*)  d_in[1];
  const float* W1   = (const float*)d_in[2];
  const float* aS1  = (const float*)d_in[3];
  const float* aD1  = (const float*)d_in[4];
  const float* b1   = (const float*)d_in[5];
  const float* W2   = (const float*)d_in[6];
  const float* aS2  = (const float*)d_in[7];
  const float* aD2  = (const float*)d_in[8];
  const float* b2   = (const float*)d_in[9];
  float* out = (float*)d_out;

  char* ws = (char*)d_ws;
  size_t off = 0;
  auto alloc = [&](size_t bytes){ void* p = ws + off; off += (bytes + 255) & ~255ull; return p; };

  unsigned short* xagg  = (unsigned short*)alloc((size_t)NT64*512*sizeof(short)); // 51.2 MB
  __half*         h1e   = (__half*)alloc((size_t)NT64*HIDDIM*sizeof(__half));     // 25.6 MB
  unsigned short* xagg2 = (unsigned short*)alloc((size_t)NT64*HIDDIM*sizeof(short)); // 25.6 MB
  __half*         xh    = (__half*)xagg2;   // alias: xh dead before xagg2 written
  __half* p16   = (__half*)alloc((size_t)4*EN*sizeof(__half));          // 6.8 MB
  float* as1    = (float*)alloc((size_t)NNODES*4*sizeof(float));
  float* ad1    = (float*)alloc((size_t)NNODES*4*sizeof(float));
  float* rdinv1 = (float*)alloc((size_t)NNODES*4*sizeof(float));
  float* as2    = (float*)alloc((size_t)NNODES*sizeof(float));
  float* ad2    = (float*)alloc((size_t)NNODES*sizeof(float));
  float* va1    = (float*)alloc(128*8*sizeof(float));
  float* va2    = (float*)alloc(256*2*sizeof(float));
  unsigned short* W1hi = (unsigned short*)alloc((size_t)128*HIDDIM*sizeof(short));
  unsigned short* W1lo = (unsigned short*)alloc((size_t)128*HIDDIM*sizeof(short));
  unsigned short* W2hi = (unsigned short*)alloc((size_t)256*HIDDIM*sizeof(short));
  unsigned short* W2lo = (unsigned short*)alloc((size_t)256*HIDDIM*sizeof(short));
  int*   counts = (int*)alloc((size_t)NNODES*sizeof(int));
  int*   offs   = (int*)alloc((size_t)(NNODES+1)*sizeof(int));
  int*   cursor = (int*)alloc((size_t)NNODES*sizeof(int));
  int*   bsum   = (int*)alloc(64*sizeof(int));
  int*   boff   = (int*)alloc(64*sizeof(int));
  int*   esrc   = (int*)alloc((size_t)EN*sizeof(int));

  const int nscan = (NNODES + SCAN_CHUNK - 1)/SCAN_CHUNK;   // 25
  const int node_grid = (NNODES + 3)/4;                     // 12500

  // fused front-end: {count ∥ wprep} -> {scan_a ∥ xh_logits} -> scan_b/c -> scatter
  hipMemsetAsync(counts, 0, (size_t)NNODES*sizeof(int), stream);
  k_pre1<<<CNT_BLOCKS + WPREP_BLOCKS, 256, 0, stream>>>(
      ei, counts, NEDGES, NNODES,
      W1, aS1, aD1, W2, aS2, aD2, W1hi, W1lo, W2hi, W2lo, va1, va2);
  k_pre2<<<SCANA_BLOCKS + node_grid, 256, 0, stream>>>(
      counts, bsum, NNODES, x, va1, xh, as1, ad1);
  k_scan_b    <<<1, 64, 0, stream>>>(bsum, boff, offs, nscan, NNODES);
  k_scan_c    <<<nscan, 256, 0, stream>>>(counts, boff, offs, cursor, NNODES);
  k_scatter   <<<NPART*120, 256, 0, stream>>>(ei, cursor, esrc, NEDGES, NNODES);

  // layer 1: 16-lane prep -> aggregate raw x -> transform (+ layer-2 logits)
  k_prep4<<<(NNODES+15)/16, 256, 0, stream>>>(as1, ad1, offs, esrc, p16, rdinv1, NNODES);
  k_agg1<<<(NNODES+7)/8, 256, 0, stream>>>(xh, p16, offs, esrc, rdinv1, xagg, NNODES);
  k_gemm1<<<NTILES, 256, 0, stream>>>(xagg, W1hi, W1lo, b1, va2, h1e, as2, ad2, NNODES);

  // layer 2: FUSED softmax+aggregate -> transform
  k_agg2<<<node_grid, 256, 0, stream>>>(h1e, as2, ad2, offs, esrc, xagg2, NNODES);
  k_gemm2<<<NTILES, 256, 0, stream>>>(xagg2, W2hi, W2lo, b2, out, NNODES);
}

// Round 16
// 290.216 us; speedup vs baseline: 1.1435x; 1.0714x over previous
//
#include <hip/hip_runtime.h>
#include <hip/hip_fp16.h>

#define NNODES 50000
#define NEDGES 800000
#define HIDDIM 256
#define EN (NEDGES + NNODES)          // CSR entries incl. self-loops
#define NTILES ((NNODES + 63)/64)     // 782 row-tiles of 64
#define NT64 (NTILES*64)              // padded row count 50048
#define NPART 8                       // dst-partitions (XCD count)
#define CNT_BLOCKS (NPART*120)        // 960 count blocks
#define WPREP_BLOCKS 385
#define SCANA_BLOCKS 25
#define DEGCAP 128                    // per-node LDS weight cap (deg ~ Poisson(17))

constexpr float NEG = 0.2f;

typedef __attribute__((ext_vector_type(8))) short short8_t;   // bf16x8 MFMA frag
typedef __attribute__((ext_vector_type(4))) float floatx4;    // f32x4 acc

__device__ __forceinline__ float lrelu(float v){ return v >= 0.f ? v : NEG*v; }

__device__ __forceinline__ unsigned short bf16_rn(float x){
  unsigned u = __float_as_uint(x);
  return (unsigned short)((u + 0x7FFFu + ((u >> 16) & 1u)) >> 16);
}

__device__ __forceinline__ float4 ldh4(const __half* p){
  union { float2 f; __half2 h[2]; } u;
  u.f = *reinterpret_cast<const float2*>(p);
  const float2 lo = __half22float2(u.h[0]);
  const float2 hi = __half22float2(u.h[1]);
  return make_float4(lo.x, lo.y, hi.x, hi.y);
}

// ---------------- k_pre1: dst-partitioned count  ∥  weight prep --------------
__global__ __launch_bounds__(256) void k_pre1(
    const int* __restrict__ ei, int* counts, int E, int n,
    const float* __restrict__ W1, const float* __restrict__ aS1, const float* __restrict__ aD1,
    const float* __restrict__ W2, const float* __restrict__ aS2, const float* __restrict__ aD2,
    unsigned short* __restrict__ W1hi, unsigned short* __restrict__ W1lo,
    unsigned short* __restrict__ W2hi, unsigned short* __restrict__ W2lo,
    float* __restrict__ va1, float* __restrict__ va2)
{
  const int t = threadIdx.x;
  if (blockIdx.x < CNT_BLOCKS){
    const int part = blockIdx.x & (NPART-1);
    const int nchunk = CNT_BLOCKS >> 3;
    const int chunk = blockIdx.x >> 3;
    const int per = n / NPART;
    const int dlo = part*per, dhi = dlo + per;
    for (int e = chunk*256 + t; e < E; e += nchunk*256){
      const int d = ei[E + e];
      if (d >= dlo && d < dhi) atomicAdd(&counts[d], 1);
    }
    return;
  }
  const int b = blockIdx.x - CNT_BLOCKS;
  if (b < 384){
    const float* W = (b < 128) ? W1 : W2;
    unsigned short* hi = (b < 128) ? W1hi : W2hi;
    unsigned short* lo = (b < 128) ? W1lo : W2lo;
    const int idx = ((b < 128) ? b : (b - 128))*256 + t;
    const int k = idx / HIDDIM, nn = idx % HIDDIM;
    const float w = W[idx];
    const unsigned short h = bf16_rn(w);
    const unsigned short l = bf16_rn(w - __uint_as_float((unsigned)h << 16));
    const int p = ((k >> 3)*HIDDIM + nn)*8 + (k & 7);
    hi[p] = h; lo[p] = l;
  } else {
    if (t < 128){
      #pragma unroll
      for (int h = 0; h < 4; ++h){
        float s = 0.f, d = 0.f;
        for (int k = 0; k < 64; ++k){
          const float w = W1[t*HIDDIM + h*64 + k];
          s = fmaf(w, aS1[h*64 + k], s);
          d = fmaf(w, aD1[h*64 + k], d);
        }
        va1[t*8 + h] = s;
        va1[t*8 + 4 + h] = d;
      }
    } else {
      for (int c = t - 128; c < 256; c += 128){
        float s = 0.f, d = 0.f;
        for (int j = 0; j < 256; ++j){
          const float w = W2[c*HIDDIM + j];
          s = fmaf(w, aS2[j], s);
          d = fmaf(w, aD2[j], d);
        }
        va2[c*2] = s; va2[c*2+1] = d;
      }
    }
  }
}

#define SCAN_CHUNK 2048
// ---------------- k_pre2: scan_a (block sums)  ∥  xh_logits ------------------
__global__ __launch_bounds__(256) void k_pre2(
    const int* __restrict__ counts, int* __restrict__ bsum, int n,
    const float* __restrict__ X, const float* __restrict__ va1,
    __half* __restrict__ xh, float* __restrict__ as1, float* __restrict__ ad1)
{
  const int t = threadIdx.x;
  if (blockIdx.x < SCANA_BLOCKS){
    __shared__ int ws[4];
    const int idx0 = blockIdx.x*SCAN_CHUNK + t*8;
    int s = 0;
    #pragma unroll
    for (int i = 0; i < 8; ++i) if (idx0 + i < n) s += counts[idx0 + i] + 1;
    for (int off = 32; off; off >>= 1) s += __shfl_xor(s, off);
    if ((t & 63) == 0) ws[t >> 6] = s;
    __syncthreads();
    if (t == 0) bsum[blockIdx.x] = ws[0] + ws[1] + ws[2] + ws[3];
    return;
  }
  const int lane = t & 63;
  const int node = (blockIdx.x - SCANA_BLOCKS)*4 + (t >> 6);
  if (node >= n) return;
  const float2 xv = *reinterpret_cast<const float2*>(X + (size_t)node*128 + 2*lane);
  *reinterpret_cast<__half2*>(xh + (size_t)node*128 + 2*lane) = __float22half2_rn(xv);

  const float4 vs0 = *reinterpret_cast<const float4*>(va1 + (2*lane)*8);
  const float4 vd0 = *reinterpret_cast<const float4*>(va1 + (2*lane)*8 + 4);
  const float4 vs1 = *reinterpret_cast<const float4*>(va1 + (2*lane+1)*8);
  const float4 vd1 = *reinterpret_cast<const float4*>(va1 + (2*lane+1)*8 + 4);
  float ps[4], pd[4];
  ps[0] = xv.x*vs0.x + xv.y*vs1.x;  pd[0] = xv.x*vd0.x + xv.y*vd1.x;
  ps[1] = xv.x*vs0.y + xv.y*vs1.y;  pd[1] = xv.x*vd0.y + xv.y*vd1.y;
  ps[2] = xv.x*vs0.z + xv.y*vs1.z;  pd[2] = xv.x*vd0.z + xv.y*vd1.z;
  ps[3] = xv.x*vs0.w + xv.y*vs1.w;  pd[3] = xv.x*vd0.w + xv.y*vd1.w;
  #pragma unroll
  for (int h = 0; h < 4; ++h)
    for (int off = 32; off; off >>= 1){
      ps[h] += __shfl_xor(ps[h], off);
      pd[h] += __shfl_xor(pd[h], off);
    }
  if (lane == 0){
    *reinterpret_cast<float4*>(as1 + (size_t)node*4) = make_float4(ps[0],ps[1],ps[2],ps[3]);
    *reinterpret_cast<float4*>(ad1 + (size_t)node*4) = make_float4(pd[0],pd[1],pd[2],pd[3]);
  }
}

// ---------------- k_scan_c: per-block base from bsum prefix (no scan_b) -----
__global__ __launch_bounds__(256) void k_scan_c(const int* __restrict__ counts,
                                                const int* __restrict__ bsum,
                                                int* __restrict__ offs,
                                                int* __restrict__ cursor, int n, int nb){
  __shared__ int sc[256];
  __shared__ int base_s;
  const int t = threadIdx.x;
  if (t == 0){
    int bse = 0;
    for (int i = 0; i < (int)blockIdx.x; ++i) bse += bsum[i];
    base_s = bse;
    if (blockIdx.x == 0){
      int tot = 0;
      for (int i = 0; i < nb; ++i) tot += bsum[i];
      offs[n] = tot;
    }
  }
  const int idx0 = blockIdx.x*SCAN_CHUNK + t*8;
  int v[8], pre[8], s = 0;
  #pragma unroll
  for (int i = 0; i < 8; ++i){
    v[i] = (idx0 + i < n) ? counts[idx0 + i] + 1 : 0;
    pre[i] = s; s += v[i];
  }
  sc[t] = s;
  __syncthreads();
  int run = s;
  for (int off = 1; off < 256; off <<= 1){
    int add = (t >= off) ? sc[t - off] : 0;
    __syncthreads();
    sc[t] += add;
    __syncthreads();
  }
  const int excl = sc[t] - run;
  const int toff = base_s + excl;
  #pragma unroll
  for (int i = 0; i < 8; ++i){
    if (idx0 + i < n){
      const int o = toff + pre[i];
      offs[idx0 + i] = o;
      cursor[idx0 + i] = o;
    }
  }
}

// dst-partitioned scatter (R9: kills write-allocate amplification)
__global__ __launch_bounds__(256) void k_scatter(const int* __restrict__ ei, int* cursor,
                          int* __restrict__ esrc, int E, int n){
  const int part = blockIdx.x & (NPART-1);
  const int nchunk = gridDim.x >> 3;
  const int chunk = blockIdx.x >> 3;
  const int per = n / NPART;
  const int dlo = part*per, dhi = dlo + per;
  const int total = E + n;
  for (int e = chunk*256 + threadIdx.x; e < total; e += nchunk*256){
    const int d = (e < E) ? ei[E + e] : (e - E);
    if (d >= dlo && d < dhi){
      const int s = (e < E) ? ei[e] : d;
      esrc[atomicAdd(&cursor[d], 1)] = s;
    }
  }
}

// ---------------- k_agg1: LDS-staged weights + gather (layer 1) --------------
// 8 nodes/block, 32 lanes per node. Phase 1: lanes compute per-edge 4-head
// weights (fp16-rounded, SHIFT trick) into LDS + dsum reduce. Phase 2: the
// R12-proven 8x-unrolled gather reads weights/src from LDS (broadcast, free).
__global__ __launch_bounds__(256) void k_agg1(
    const __half* __restrict__ xh,
    const float* __restrict__ as1, const float* __restrict__ ad1,
    const int* __restrict__ offs, const int* __restrict__ esrc,
    unsigned short* __restrict__ xagg, int n)
{
  constexpr float SHIFT = 2.0f;
  __shared__ int    sl[8][DEGCAP];
  __shared__ float2 wl[8][DEGCAP];
  __shared__ float  rdl[8][4];
  const int g = threadIdx.x >> 5;
  const int l2 = threadIdx.x & 31;
  const int node = blockIdx.x*8 + g;
  int start = 0, end = 0;
  float adv[4] = {0.f, 0.f, 0.f, 0.f};
  if (node < n){
    start = offs[node]; end = offs[node+1];
    const float4 adv4 = *reinterpret_cast<const float4*>(ad1 + (size_t)node*4);
    adv[0] = adv4.x; adv[1] = adv4.y; adv[2] = adv4.z; adv[3] = adv4.w;
  }
  const int deg = end - start;

  // phase 1: weights into LDS + dsum
  float dsum[4] = {0.f, 0.f, 0.f, 0.f};
  for (int i = l2; i < deg; i += 32){
    const int s = esrc[start + i];
    const float4 av = *reinterpret_cast<const float4*>(as1 + (size_t)s*4);
    const float a[4] = {av.x, av.y, av.z, av.w};
    union { float2 f; __half2 h2[2]; } o;
    float wq[4];
    #pragma unroll
    for (int h = 0; h < 4; ++h){
      const __half w16 = __float2half(__expf(lrelu(a[h] + adv[h]) - SHIFT));
      wq[h] = __half2float(w16);
      dsum[h] += wq[h];
    }
    if (i < DEGCAP){
      o.h2[0] = __half2{__float2half(wq[0]), __float2half(wq[1])};
      o.h2[1] = __half2{__float2half(wq[2]), __float2half(wq[3])};
      sl[g][i] = s;
      wl[g][i] = o.f;
    }
  }
  #pragma unroll
  for (int h = 0; h < 4; ++h)
    for (int off = 16; off; off >>= 1) dsum[h] += __shfl_xor(dsum[h], off);
  if (l2 == 0){
    #pragma unroll
    for (int h = 0; h < 4; ++h) rdl[g][h] = 1.f/(dsum[h] + 1e-16f);
  }
  __syncthreads();
  if (node >= n) return;

  // phase 2: gather x rows, weights broadcast from LDS
  const __half* hp = xh + 4*l2;
  const int dcap = (deg < DEGCAP) ? deg : DEGCAP;
  float acc[4][4] = {};   // [head][ch]
  int i = 0;
  for (; i + 8 <= dcap; i += 8){
    int s[8]; float2 pv[8]; float2 xv[8];
    #pragma unroll
    for (int j = 0; j < 8; ++j) s[j] = sl[g][i+j];
    #pragma unroll
    for (int j = 0; j < 8; ++j) pv[j] = wl[g][i+j];
    #pragma unroll
    for (int j = 0; j < 8; ++j) xv[j] = *reinterpret_cast<const float2*>(hp + (size_t)s[j]*128);
    #pragma unroll
    for (int j = 0; j < 8; ++j){
      union { float2 f; __half2 h2[2]; } ux; ux.f = xv[j];
      const float2 x01 = __half22float2(ux.h2[0]);
      const float2 x23 = __half22float2(ux.h2[1]);
      union { float2 f; __half2 h2[2]; } up; up.f = pv[j];
      const float2 p01 = __half22float2(up.h2[0]);
      const float2 p23 = __half22float2(up.h2[1]);
      const float ph[4] = {p01.x, p01.y, p23.x, p23.y};
      const float xc[4] = {x01.x, x01.y, x23.x, x23.y};
      #pragma unroll
      for (int h = 0; h < 4; ++h)
        #pragma unroll
        for (int c = 0; c < 4; ++c)
          acc[h][c] = fmaf(ph[h], xc[c], acc[h][c]);
    }
  }
  for (; i < dcap; ++i){
    const int s = sl[g][i];
    union { float2 f; __half2 h2[2]; } ux;
    ux.f = *reinterpret_cast<const float2*>(hp + (size_t)s*128);
    const float2 x01 = __half22float2(ux.h2[0]);
    const float2 x23 = __half22float2(ux.h2[1]);
    union { float2 f; __half2 h2[2]; } up; up.f = wl[g][i];
    const float2 p01 = __half22float2(up.h2[0]);
    const float2 p23 = __half22float2(up.h2[1]);
    const float ph[4] = {p01.x, p01.y, p23.x, p23.y};
    const float xc[4] = {x01.x, x01.y, x23.x, x23.y};
    #pragma unroll
    for (int h = 0; h < 4; ++h)
      #pragma unroll
      for (int c = 0; c < 4; ++c)
        acc[h][c] = fmaf(ph[h], xc[c], acc[h][c]);
  }
  // ultra-rare tail (deg > DEGCAP): recompute weights inline
  for (int e = start + DEGCAP; e < end; ++e){
    const int s = esrc[e];
    const float4 av = *reinterpret_cast<const float4*>(as1 + (size_t)s*4);
    const float a[4] = {av.x, av.y, av.z, av.w};
    float ph[4];
    #pragma unroll
    for (int h = 0; h < 4; ++h)
      ph[h] = __expf(lrelu(a[h] + adv[h]) - SHIFT);
    union { float2 f; __half2 h2[2]; } ux;
    ux.f = *reinterpret_cast<const float2*>(hp + (size_t)s*128);
    const float2 x01 = __half22float2(ux.h2[0]);
    const float2 x23 = __half22float2(ux.h2[1]);
    const float xc[4] = {x01.x, x01.y, x23.x, x23.y};
    #pragma unroll
    for (int h = 0; h < 4; ++h)
      #pragma unroll
      for (int c = 0; c < 4; ++c)
        acc[h][c] = fmaf(ph[h], xc[c], acc[h][c]);
  }

  #pragma unroll
  for (int h = 0; h < 4; ++h){
    const float rd = rdl[g][h];
    uint2 pk;
    pk.x = (unsigned)bf16_rn(acc[h][0]*rd) | ((unsigned)bf16_rn(acc[h][1]*rd) << 16);
    pk.y = (unsigned)bf16_rn(acc[h][2]*rd) | ((unsigned)bf16_rn(acc[h][3]*rd) << 16);
    *reinterpret_cast<uint2*>(xagg + (size_t)node*512 + h*128 + 4*l2) = pk;
  }
}

// ---------------- k_gemm1: h1e = ELU(xagg @ blockdiag(W1) + b1) -------------
__global__ __launch_bounds__(256) void k_gemm1(
    const unsigned short* __restrict__ Xagg,
    const unsigned short* __restrict__ Bhi, const unsigned short* __restrict__ Blo,
    const float* __restrict__ b1, const float* __restrict__ va2,
    __half* __restrict__ h1e, float* __restrict__ as2, float* __restrict__ ad2, int M)
{
  __shared__ float lred_s[64][4], lred_d[64][4];
  const int tid = threadIdx.x;
  const int w = tid >> 6, l = tid & 63;
  const int lr = l & 15, lg = l >> 4;
  const int row0 = blockIdx.x*64;
  const int n0 = w*64;
  floatx4 acc[4][4] = {};

  for (int ks = 0; ks < 4; ++ks){
    short8_t a_[4], bh[4], bl[4];
    #pragma unroll
    for (int m = 0; m < 4; ++m){
      const size_t ao = (size_t)(row0 + 16*m + lr)*512 + w*128 + ks*32 + lg*8;
      a_[m] = *reinterpret_cast<const short8_t*>(&Xagg[ao]);
    }
    #pragma unroll
    for (int n = 0; n < 4; ++n){
      const int boff = (((ks*4 + lg)*HIDDIM) + n0 + 16*n + lr)*8;
      bh[n] = *reinterpret_cast<const short8_t*>(&Bhi[boff]);
      bl[n] = *reinterpret_cast<const short8_t*>(&Blo[boff]);
    }
    #pragma unroll
    for (int m = 0; m < 4; ++m)
      #pragma unroll
      for (int n = 0; n < 4; ++n){
        acc[m][n] = __builtin_amdgcn_mfma_f32_16x16x32_bf16(a_[m], bh[n], acc[m][n], 0,0,0);
        acc[m][n] = __builtin_amdgcn_mfma_f32_16x16x32_bf16(a_[m], bl[n], acc[m][n], 0,0,0);
      }
  }

  float bcol[4], v2s[4], v2d[4];
  #pragma unroll
  for (int n = 0; n < 4; ++n){
    const int col = n0 + 16*n + lr;
    bcol[n] = b1[col];
    v2s[n] = va2[col*2];
    v2d[n] = va2[col*2+1];
  }
  #pragma unroll
  for (int m = 0; m < 4; ++m){
    #pragma unroll
    for (int r = 0; r < 4; ++r){
      const int row = row0 + 16*m + lg*4 + r;
      float ps = 0.f, pd = 0.f;
      #pragma unroll
      for (int n = 0; n < 4; ++n){
        float v = acc[m][n][r] + bcol[n];
        v = v > 0.f ? v : __expf(v) - 1.f;           // ELU
        if (row < M) h1e[(size_t)row*HIDDIM + n0 + 16*n + lr] = __float2half(v);
        ps = fmaf(v, v2s[n], ps);
        pd = fmaf(v, v2d[n], pd);
      }
      #pragma unroll
      for (int off = 1; off <= 8; off <<= 1){
        ps += __shfl_xor(ps, off);
        pd += __shfl_xor(pd, off);
      }
      const int rloc = 16*m + lg*4 + r;
      if (lr == 0){ lred_s[rloc][w] = ps; lred_d[rloc][w] = pd; }
    }
  }
  __syncthreads();
  if (tid < 64 && row0 + tid < M){
    as2[row0+tid] = lred_s[tid][0]+lred_s[tid][1]+lred_s[tid][2]+lred_s[tid][3];
    ad2[row0+tid] = lred_d[tid][0]+lred_d[tid][1]+lred_d[tid][2]+lred_d[tid][3];
  }
}

// ---------------- k_agg2: fused softmax + gather (layer 2) ------------------
__global__ __launch_bounds__(256) void k_agg2(
    const __half* __restrict__ Hs,
    const float* __restrict__ as2, const float* __restrict__ ad2,
    const int* __restrict__ offs, const int* __restrict__ esrc,
    unsigned short* __restrict__ xagg2, int n)
{
  constexpr float SHIFT = 4.0f;
  const int lane = threadIdx.x & 63;
  const int node = blockIdx.x*4 + (threadIdx.x >> 6);
  if (node >= n) return;
  const int start = offs[node], end = offs[node+1];
  const float adn = ad2[node];
  const __half* hp = Hs + 4*lane;

  float4 a0 = {0,0,0,0}, a1 = {0,0,0,0}, a2 = {0,0,0,0}, a3 = {0,0,0,0};
  float dsum = 0.f;
  int e = start;
  for (; e + 4 <= end; e += 4){
    const int s0 = esrc[e+0], s1 = esrc[e+1], s2 = esrc[e+2], s3 = esrc[e+3];
    const float w0 = __expf(lrelu(as2[s0] + adn) - SHIFT);
    const float w1 = __expf(lrelu(as2[s1] + adn) - SHIFT);
    const float w2 = __expf(lrelu(as2[s2] + adn) - SHIFT);
    const float w3 = __expf(lrelu(as2[s3] + adn) - SHIFT);
    dsum += (w0 + w1) + (w2 + w3);
    const float4 h0 = ldh4(hp + (size_t)s0*HIDDIM);
    const float4 h1 = ldh4(hp + (size_t)s1*HIDDIM);
    const float4 h2 = ldh4(hp + (size_t)s2*HIDDIM);
    const float4 h3 = ldh4(hp + (size_t)s3*HIDDIM);
    a0.x = fmaf(w0, h0.x, a0.x); a0.y = fmaf(w0, h0.y, a0.y);
    a0.z = fmaf(w0, h0.z, a0.z); a0.w = fmaf(w0, h0.w, a0.w);
    a1.x = fmaf(w1, h1.x, a1.x); a1.y = fmaf(w1, h1.y, a1.y);
    a1.z = fmaf(w1, h1.z, a1.z); a1.w = fmaf(w1, h1.w, a1.w);
    a2.x = fmaf(w2, h2.x, a2.x); a2.y = fmaf(w2, h2.y, a2.y);
    a2.z = fmaf(w2, h2.z, a2.z); a2.w = fmaf(w2, h2.w, a2.w);
    a3.x = fmaf(w3, h3.x, a3.x); a3.y = fmaf(w3, h3.y, a3.y);
    a3.z = fmaf(w3, h3.z, a3.z); a3.w = fmaf(w3, h3.w, a3.w);
  }
  for (; e < end; ++e){
    const int s = esrc[e];
    const float w = __expf(lrelu(as2[s] + adn) - SHIFT);
    dsum += w;
    const float4 hv = ldh4(hp + (size_t)s*HIDDIM);
    a0.x = fmaf(w, hv.x, a0.x); a0.y = fmaf(w, hv.y, a0.y);
    a0.z = fmaf(w, hv.z, a0.z); a0.w = fmaf(w, hv.w, a0.w);
  }
  const float rd = 1.f/(dsum + 1e-16f);
  float4 acc;
  acc.x = ((a0.x + a1.x) + (a2.x + a3.x)) * rd;
  acc.y = ((a0.y + a1.y) + (a2.y + a3.y)) * rd;
  acc.z = ((a0.z + a1.z) + (a2.z + a3.z)) * rd;
  acc.w = ((a0.w + a1.w) + (a2.w + a3.w)) * rd;

  uint2 pk;
  pk.x = (unsigned)bf16_rn(acc.x) | ((unsigned)bf16_rn(acc.y) << 16);
  pk.y = (unsigned)bf16_rn(acc.z) | ((unsigned)bf16_rn(acc.w) << 16);
  *reinterpret_cast<uint2*>(xagg2 + (size_t)node*HIDDIM + 4*lane) = pk;
}

// ---------------- k_gemm2: out = xagg2 @ W2 + b2 ----------------------------
__global__ __launch_bounds__(256) void k_gemm2(
    const unsigned short* __restrict__ Xagg2,
    const unsigned short* __restrict__ Bhi, const unsigned short* __restrict__ Blo,
    const float* __restrict__ b2, float* __restrict__ Out, int M)
{
  const int tid = threadIdx.x;
  const int w = tid >> 6, l = tid & 63;
  const int lr = l & 15, lg = l >> 4;
  const int row0 = blockIdx.x*64;
  const int n0 = w*64;
  floatx4 acc[4][4] = {};

  for (int ks = 0; ks < 8; ++ks){
    short8_t a_[4], bh[4], bl[4];
    #pragma unroll
    for (int m = 0; m < 4; ++m){
      const size_t ao = (size_t)(row0 + 16*m + lr)*HIDDIM + ks*32 + lg*8;
      a_[m] = *reinterpret_cast<const short8_t*>(&Xagg2[ao]);
    }
    #pragma unroll
    for (int n = 0; n < 4; ++n){
      const int boff = (((ks*4 + lg)*HIDDIM) + n0 + 16*n + lr)*8;
      bh[n] = *reinterpret_cast<const short8_t*>(&Bhi[boff]);
      bl[n] = *reinterpret_cast<const short8_t*>(&Blo[boff]);
    }
    #pragma unroll
    for (int m = 0; m < 4; ++m)
      #pragma unroll
      for (int n = 0; n < 4; ++n){
        acc[m][n] = __builtin_amdgcn_mfma_f32_16x16x32_bf16(a_[m], bh[n], acc[m][n], 0,0,0);
        acc[m][n] = __builtin_amdgcn_mfma_f32_16x16x32_bf16(a_[m], bl[n], acc[m][n], 0,0,0);
      }
  }

  float bcol[4];
  #pragma unroll
  for (int n = 0; n < 4; ++n) bcol[n] = b2[n0 + 16*n + lr];
  #pragma unroll
  for (int m = 0; m < 4; ++m){
    #pragma unroll
    for (int r = 0; r < 4; ++r){
      const int row = row0 + 16*m + lg*4 + r;
      if (row < M){
        #pragma unroll
        for (int n = 0; n < 4; ++n)
          Out[(size_t)row*HIDDIM + n0 + 16*n + lr] = acc[m][n][r] + bcol[n];
      }
    }
  }
}

// ---------------- launch ----------------
extern "C" void kernel_launch(void* const* d_in, const int* in_sizes, int n_in,
                              void* d_out, int out_size, void* d_ws, size_t ws_size,
                              hipStream_t stream)
{
  const float* x    = (const float*)d_in[0];
  const int*   ei   = (const int*)  d_in[1];
  const float* W1   = (const float*)d_in[2];
  const float* aS1  = (const float*)d_in[3];
  const float* aD1  = (const float*)d_in[4];
  const float* b1   = (const float*)d_in[5];
  const float* W2   = (const float*)d_in[6];
  const float* aS2  = (const float*)d_in[7];
  const float* aD2  = (const float*)d_in[8];
  const float* b2   = (const float*)d_in[9];
  float* out = (float*)d_out;

  char* ws = (char*)d_ws;
  size_t off = 0;
  auto alloc = [&](size_t bytes){ void* p = ws + off; off += (bytes + 255) & ~255ull; return p; };

  unsigned short* xagg  = (unsigned short*)alloc((size_t)NT64*512*sizeof(short)); // 51.2 MB
  __half*         h1e   = (__half*)alloc((size_t)NT64*HIDDIM*sizeof(__half));     // 25.6 MB
  unsigned short* xagg2 = (unsigned short*)alloc((size_t)NT64*HIDDIM*sizeof(short)); // 25.6 MB
  __half*         xh    = (__half*)xagg2;   // alias: xh dead before xagg2 written
  float* as1    = (float*)alloc((size_t)NNODES*4*sizeof(float));
  float* ad1    = (float*)alloc((size_t)NNODES*4*sizeof(float));
  float* as2    = (float*)alloc((size_t)NNODES*sizeof(float));
  float* ad2    = (float*)alloc((size_t)NNODES*sizeof(float));
  float* va1    = (float*)alloc(128*8*sizeof(float));
  float* va2    = (float*)alloc(256*2*sizeof(float));
  unsigned short* W1hi = (unsigned short*)alloc((size_t)128*HIDDIM*sizeof(short));
  unsigned short* W1lo = (unsigned short*)alloc((size_t)128*HIDDIM*sizeof(short));
  unsigned short* W2hi = (unsigned short*)alloc((size_t)256*HIDDIM*sizeof(short));
  unsigned short* W2lo = (unsigned short*)alloc((size_t)256*HIDDIM*sizeof(short));
  int*   counts = (int*)alloc((size_t)NNODES*sizeof(int));
  int*   offs   = (int*)alloc((size_t)(NNODES+1)*sizeof(int));
  int*   cursor = (int*)alloc((size_t)NNODES*sizeof(int));
  int*   bsum   = (int*)alloc(64*sizeof(int));
  int*   esrc   = (int*)alloc((size_t)EN*sizeof(int));

  const int nscan = (NNODES + SCAN_CHUNK - 1)/SCAN_CHUNK;   // 25
  const int node_grid = (NNODES + 3)/4;                     // 12500

  // fused front-end: {count ∥ wprep} -> {scan_a ∥ xh_logits} -> scan_c -> scatter
  hipMemsetAsync(counts, 0, (size_t)NNODES*sizeof(int), stream);
  k_pre1<<<CNT_BLOCKS + WPREP_BLOCKS, 256, 0, stream>>>(
      ei, counts, NEDGES, NNODES,
      W1, aS1, aD1, W2, aS2, aD2, W1hi, W1lo, W2hi, W2lo, va1, va2);
  k_pre2<<<SCANA_BLOCKS + node_grid, 256, 0, stream>>>(
      counts, bsum, NNODES, x, va1, xh, as1, ad1);
  k_scan_c    <<<nscan, 256, 0, stream>>>(counts, bsum, offs, cursor, NNODES, nscan);
  k_scatter   <<<NPART*120, 256, 0, stream>>>(ei, cursor, esrc, NEDGES, NNODES);

  // layer 1: LDS-staged weights + aggregate raw x -> transform (+ layer-2 logits)
  k_agg1<<<(NNODES+7)/8, 256, 0, stream>>>(xh, as1, ad1, offs, esrc, xagg, NNODES);
  k_gemm1<<<NTILES, 256, 0, stream>>>(xagg, W1hi, W1lo, b1, va2, h1e, as2, ad2, NNODES);

  // layer 2: FUSED softmax+aggregate -> transform
  k_agg2<<<node_grid, 256, 0, stream>>>(h1e, as2, ad2, offs, esrc, xagg2, NNODES);
  k_gemm2<<<NTILES, 256, 0, stream>>>(xagg2, W2hi, W2lo, b2, out, NNODES);
}